// Round 12
// baseline (2092.843 us; speedup 1.0000x reference)
//
#include <hip/hip_runtime.h>
#include <math.h>

#define NFFT   1024
#define NHALF  512
#define HOPSZ  256
#define NMELS  80
#define NFREQ  513
#define BATCH  8
#define TFRAMES 1024
#define PADW   512
#define LPAD   (NFFT + (TFRAMES - 1) * HOPSZ)   // 262912
#define LOUT   (LPAD - 2 * PADW)                // 261888
#define NITER  60
#define PI_D   3.14159265358979323846

#define CHUNKF 4                                // frames per chunk
#define CSPAN  1792                             // 1024 + 3*256
#define NCHUNK (TFRAMES / CHUNKF)               // 256

// padding for the (old, init-only) radix-4 FFT
#define PAD(p) ((p) + ((p) >> 5))
#define NPAD   (NHALF + (NHALF >> 5))           // 528

// padding for the hot-loop radix-8 C buffer (float2 units): +1 per 8
#define PC(p)  ((p) + ((p) >> 3))
#define C_SZ   576                              // PC(511)=574 < 576

// ---------------------------------------------------------------- init tables
__global__ void k_init_tables(float* __restrict__ twr, float* __restrict__ twi,
                              float* __restrict__ t5r, float* __restrict__ t5i,
                              float* __restrict__ win) {
    int j = blockIdx.x * 256 + threadIdx.x;
    if (j < NHALF) {
        double th = -2.0 * PI_D * (double)j / (double)NFFT;
        twr[j] = (float)cos(th);
        twi[j] = (float)sin(th);
    }
    if (j < 128) {
        double th = -2.0 * PI_D * (double)j / 512.0;
        t5r[j] = (float)cos(th);
        t5i[j] = (float)sin(th);
    }
    if (j < NFFT) {
        win[j] = (float)(0.5 - 0.5 * cos(2.0 * PI_D * (double)j / (double)NFFT));
    }
}

__global__ void k_env(const float* __restrict__ win, float* __restrict__ envinv) {
    int i = blockIdx.x * 256 + threadIdx.x;
    if (i >= LPAD) return;
    int thi = i / HOPSZ; if (thi > TFRAMES - 1) thi = TFRAMES - 1;
    int d = i - (NFFT - 1);
    int tlo = (d > 0) ? (d + HOPSZ - 1) / HOPSZ : 0;
    float e = 0.f;
    for (int t = tlo; t <= thi; ++t) { float w = win[i - t * HOPSZ]; e += w * w; }
    envinv[i] = (e > 1e-11f) ? (1.0f / e) : 1.0f;
}

__global__ void k_fbt(const float* __restrict__ fb, float* __restrict__ fbT) {
    int i = blockIdx.x * 256 + threadIdx.x;
    if (i < NFREQ * NMELS) {
        int k = i / NMELS, m = i - k * NMELS;
        fbT[m * NFREQ + k] = fb[i];
    }
}

// mag[(b*1024+t)*513+k], tiled 16 t per block
__global__ __launch_bounds__(256) void k_mag(const float* __restrict__ mel,
                                             const float* __restrict__ fbT,
                                             float* __restrict__ mag) {
    __shared__ float sm[NMELS * 16];
    int b = blockIdx.y, t0 = blockIdx.x * 16, tid = threadIdx.x;
    for (int idx = tid; idx < NMELS * 16; idx += 256) {
        int m = idx >> 4, tt = idx & 15;
        sm[idx] = expf(mel[(size_t)(b * NMELS + m) * TFRAMES + (t0 + tt)]);
    }
    __syncthreads();
    for (int k = tid; k < NFREQ; k += 256) {
        float acc[16];
        #pragma unroll
        for (int tt = 0; tt < 16; ++tt) acc[tt] = 0.f;
        for (int m = 0; m < NMELS; ++m) {
            float w = fbT[m * NFREQ + k];
            #pragma unroll
            for (int tt = 0; tt < 16; ++tt) acc[tt] += w * sm[m * 16 + tt];
        }
        #pragma unroll
        for (int tt = 0; tt < 16; ++tt)
            mag[(size_t)((b << 10) + t0 + tt) * NFREQ + k] = fmaxf(acc[tt], 0.f);
    }
}

// ===================== old radix-4 path (init kernel only, verified round 6)
__device__ __forceinline__ void fft512_m(float* xr, float* xi, float* yr, float* yi,
                                         const float* t5r, const float* t5i,
                                         int l, float sgn) {
    float *ar = xr, *ai = xi, *br = yr, *bi = yi;
    #pragma unroll
    for (int st = 0; st < 4; ++st) {
        int s = 1 << (2 * st);
        __syncthreads();
        int j = l;
        int hi = j & ~(s - 1);
        int o1 = j + 3 * hi;
        float v0r = ar[PAD(j)],       v0i = ai[PAD(j)];
        float v1r = ar[PAD(j + 128)], v1i = ai[PAD(j + 128)];
        float v2r = ar[PAD(j + 256)], v2i = ai[PAD(j + 256)];
        float v3r = ar[PAD(j + 384)], v3i = ai[PAD(j + 384)];
        float a_r = v0r + v2r, a_i = v0i + v2i;
        float b_r = v0r - v2r, b_i = v0i - v2i;
        float c_r = v1r + v3r, c_i = v1i + v3i;
        float d_r = v1r - v3r, d_i = v1i - v3i;
        float X0r = a_r + c_r, X0i = a_i + c_i;
        float X2r = a_r - c_r, X2i = a_i - c_i;
        float X1r = b_r + sgn * d_i, X1i = b_i - sgn * d_r;
        float X3r = b_r - sgn * d_i, X3i = b_i + sgn * d_r;
        float w1r = t5r[hi], w1i = sgn * t5i[hi];
        float w2r = w1r * w1r - w1i * w1i, w2i = 2.f * w1r * w1i;
        float w3r = w2r * w1r - w2i * w1i, w3i = w2r * w1i + w2i * w1r;
        br[PAD(o1)]         = X0r;
        bi[PAD(o1)]         = X0i;
        br[PAD(o1 + s)]     = X1r * w1r - X1i * w1i;
        bi[PAD(o1 + s)]     = X1r * w1i + X1i * w1r;
        br[PAD(o1 + 2*s)]   = X2r * w2r - X2i * w2i;
        bi[PAD(o1 + 2*s)]   = X2r * w2i + X2i * w2r;
        br[PAD(o1 + 3*s)]   = X3r * w3r - X3i * w3i;
        bi[PAD(o1 + 3*s)]   = X3r * w3i + X3i * w3r;
        float* t0 = ar; ar = br; br = t0;
        float* t1 = ai; ai = bi; bi = t1;
    }
    __syncthreads();
    #pragma unroll
    for (int r = 0; r < 2; ++r) {
        int j = l + r * 128;
        float x0r = ar[PAD(j)],       x0i = ai[PAD(j)];
        float x1r = ar[PAD(j + 256)], x1i = ai[PAD(j + 256)];
        br[PAD(j)]       = x0r + x1r;
        bi[PAD(j)]       = x0i + x1i;
        br[PAD(j + 256)] = x0r - x1r;
        bi[PAD(j + 256)] = x0i - x1i;
    }
}

__device__ __forceinline__ void chunk_ola4(float (*Yr)[NPAD], float (*Yi)[NPAD],
                                           const float* swin, float* Po, int tid) {
    const float SC = 1.0f / 512.0f;
    for (int j = tid; j < CSPAN; j += 512) {
        float acc = 0.f;
        #pragma unroll
        for (int gg = 0; gg < CHUNKF; ++gg) {
            int p = j - 256 * gg;
            if (p >= 0 && p < NFFT) {
                float yv = (p & 1) ? Yi[gg][PAD(p >> 1)] : Yr[gg][PAD(p >> 1)];
                acc += yv * swin[p];
            }
        }
        Po[j] = acc * SC;
    }
}

// -------------------- init: P0 from mag * e^{i 2pi ang} (verified round 6)
__global__ __launch_bounds__(512) void k_init4(
        const float* __restrict__ mag, const float* __restrict__ ang,
        const float* __restrict__ gtwr, const float* __restrict__ gtwi,
        const float* __restrict__ gt5r, const float* __restrict__ gt5i,
        const float* __restrict__ win, float* __restrict__ Pout) {
    __shared__ float swin[NFFT];
    __shared__ float Xr[CHUNKF][NPAD], Xi[CHUNKF][NPAD];
    __shared__ float Yr[CHUNKF][NPAD], Yi[CHUNKF][NPAD];
    __shared__ float t5r[128], t5i[128];
    int blk = blockIdx.x; int b = blk >> 8; int c = blk & (NCHUNK - 1);
    int tid = threadIdx.x; int g = tid >> 7; int l = tid & 127;
    if (tid < 128) { t5r[tid] = gt5r[tid]; t5i[tid] = gt5i[tid]; }
    for (int q = tid; q < NFFT; q += 512) swin[q] = win[q];
    int ft = CHUNKF * c + g;
    const float* mrow = mag + (size_t)(b * TFRAMES + ft) * NFREQ;
    const float TWO_PI = 6.283185307179586477f;
    if (l == 0) {
        float a0, s0, c0;
        a0 = ang[((size_t)(b * NFREQ + 0)) * TFRAMES + ft] * TWO_PI;
        sincosf(a0, &s0, &c0);
        float p0 = mrow[0] * c0;
        a0 = ang[((size_t)(b * NFREQ + 512)) * TFRAMES + ft] * TWO_PI;
        sincosf(a0, &s0, &c0);
        float p512 = mrow[512] * c0;
        Xr[g][PAD(0)] = 0.5f * (p0 + p512);
        Xi[g][PAD(0)] = 0.5f * (p0 - p512);
        a0 = ang[((size_t)(b * NFREQ + 256)) * TFRAMES + ft] * TWO_PI;
        sincosf(a0, &s0, &c0);
        Xr[g][PAD(256)] = mrow[256] * c0;
        Xi[g][PAD(256)] = -(mrow[256] * s0);
    }
    #pragma unroll
    for (int q2 = 0; q2 < 2; ++q2) {
        int k = l + q2 * 128;
        if (k == 0) continue;
        int j = 512 - k;
        float ak = ang[((size_t)(b * NFREQ + k)) * TFRAMES + ft] * TWO_PI;
        float aj = ang[((size_t)(b * NFREQ + j)) * TFRAMES + ft] * TWO_PI;
        float sk, ck, sj, cj;
        sincosf(ak, &sk, &ck); sincosf(aj, &sj, &cj);
        float pkr = mrow[k] * ck, pki = mrow[k] * sk;
        float pjr = mrow[j] * cj, pji = mrow[j] * sj;
        float Wr = gtwr[k], Wi = gtwi[k];
        float Cr = 0.5f * (pkr + pjr), Ci = 0.5f * (pki - pji);
        float Dr = 0.5f * (pkr - pjr), Di = 0.5f * (pki + pji);
        float U = Wr * Di - Wi * Dr, V = Wr * Dr + Wi * Di;
        Xr[g][PAD(k)] = Cr - U;  Xi[g][PAD(k)] = Ci + V;
        Xr[g][PAD(j)] = Cr + U;  Xi[g][PAD(j)] = -Ci + V;
    }
    fft512_m(Xr[g], Xi[g], Yr[g], Yi[g], t5r, t5i, l, -1.f);
    __syncthreads();
    chunk_ola4(Yr, Yi, swin, Pout + ((size_t)b * NCHUNK + c) * CSPAN, tid);
}

// ===================== wave-local radix-8 machinery (hot loop) ==============
__device__ __forceinline__ float2 cmul(float2 a, float2 b) {
    return make_float2(a.x * b.x - a.y * b.y, a.x * b.y + a.y * b.x);
}

// in-register 8-pt DFT; sgn=+1 forward, -1 inverse (verified round 7)
__device__ __forceinline__ void dft8(float2 v[8], float sgn) {
    const float s2 = 0.70710678118654752f;
    float ar = v[0].x + v[4].x, ai = v[0].y + v[4].y;
    float br = v[0].x - v[4].x, bi = v[0].y - v[4].y;
    float cr = v[2].x + v[6].x, ci = v[2].y + v[6].y;
    float dr = v[2].x - v[6].x, di = v[2].y - v[6].y;
    float2 E0 = make_float2(ar + cr, ai + ci);
    float2 E2 = make_float2(ar - cr, ai - ci);
    float2 E1 = make_float2(br + sgn * di, bi - sgn * dr);
    float2 E3 = make_float2(br - sgn * di, bi + sgn * dr);
    float ar2 = v[1].x + v[5].x, ai2 = v[1].y + v[5].y;
    float br2 = v[1].x - v[5].x, bi2 = v[1].y - v[5].y;
    float cr2 = v[3].x + v[7].x, ci2 = v[3].y + v[7].y;
    float dr2 = v[3].x - v[7].x, di2 = v[3].y - v[7].y;
    float2 O0 = make_float2(ar2 + cr2, ai2 + ci2);
    float2 O2 = make_float2(ar2 - cr2, ai2 - ci2);
    float2 O1 = make_float2(br2 + sgn * di2, bi2 - sgn * dr2);
    float2 O3 = make_float2(br2 - sgn * di2, bi2 + sgn * dr2);
    float2 T1 = make_float2((O1.x + sgn * O1.y) * s2, (O1.y - sgn * O1.x) * s2);
    float2 T2 = make_float2(sgn * O2.y, -sgn * O2.x);
    float2 T3 = make_float2((-O3.x + sgn * O3.y) * s2, (-O3.y - sgn * O3.x) * s2);
    v[0] = make_float2(E0.x + O0.x, E0.y + O0.y);
    v[4] = make_float2(E0.x - O0.x, E0.y - O0.y);
    v[1] = make_float2(E1.x + T1.x, E1.y + T1.y);
    v[5] = make_float2(E1.x - T1.x, E1.y - T1.y);
    v[2] = make_float2(E2.x + T2.x, E2.y + T2.y);
    v[6] = make_float2(E2.x - T2.x, E2.y - T2.y);
    v[3] = make_float2(E3.x + T3.x, E3.y + T3.y);
    v[7] = make_float2(E3.x - T3.x, E3.y - T3.y);
}

// apply v[m] *= W^m for m=1..7, W=(wr,wi)  (low-register sequential chain)
__device__ __forceinline__ void twchain(float2 v[8], float wr, float wi) {
    float2 w = make_float2(wr, wi), cur = w;
    #pragma unroll
    for (int m = 1; m < 8; ++m) { v[m] = cmul(v[m], cur); cur = cmul(cur, w); }
}

// stage s=8: read Cb[t+64m] (free), dft8, twiddle, write Cb[64a+r+8m] (4-way)
__device__ __forceinline__ void r8_stage2(float2* Cb, const float* gtwr,
                                          const float* gtwi, int t, float sgn) {
    float2 u[8];
    #pragma unroll
    for (int m = 0; m < 8; ++m) u[m] = Cb[PC(t + 64 * m)];
    dft8(u, sgn);
    int a = t >> 3;
    twchain(u, gtwr[16 * a], sgn * gtwi[16 * a]);      // W_64^a = W_1024^{16a}
    int o1 = 64 * a + (t & 7);
    #pragma unroll
    for (int m = 0; m < 8; ++m) Cb[PC(o1 + 8 * m)] = u[m];
}

// -------- hot GL iteration (round-11 structure + no-swin for 8 blocks/CU):
//  LDS = C buffer only (18432 B) -> exactly 8 blocks/CU, zero residency tail;
//  window read from global (coalesced float2 / float, L1-resident 4KB table).
__global__ __launch_bounds__(256, 4) void k_gl8(
        const float* __restrict__ Pin, const float* __restrict__ mag,
        const float* __restrict__ envinv,
        const float* __restrict__ gtwr, const float* __restrict__ gtwi,
        const float* __restrict__ win, float* __restrict__ Pout) {
    __shared__ __align__(16) unsigned char smem_raw[CHUNKF * C_SZ * sizeof(float2)];
    float2 (*C)[C_SZ] = reinterpret_cast<float2(*)[C_SZ]>(smem_raw);
    float*  sigwin  = reinterpret_cast<float*>(smem_raw);   // first 7168 B of C
    float2* sigwin2 = reinterpret_cast<float2*>(smem_raw);
    int blk = blockIdx.x; int b = blk >> 8; int c = blk & (NCHUNK - 1);
    int tid = threadIdx.x; int g = tid >> 6; int t = tid & 63;
    // ---- stage normalized signal window (identical to verified round 6)
    const float* Pb = Pin + (size_t)b * NCHUNK * CSPAN;
    for (int q = tid; q < CSPAN; q += 256) {
        float v = Pb[c * CSPAN + q];
        if (q < 768 && c > 0)              v += Pb[(c - 1) * CSPAN + q + 1024];
        if (q >= 1024 && c < NCHUNK - 1)   v += Pb[(c + 1) * CSPAN + q - 1024];
        sigwin[q] = v * envinv[1024 * c + q];
    }
    __syncthreads();
    float2* Cb = C[g];
    const float2* win2 = (const float2*)win;       // global, L1-resident
    int ft = CHUNKF * c + g;
    const float* mrow = mag + (size_t)(b * TFRAMES + ft) * NFREQ;
    // ---- z-pack into registers: z[m] = s[2mp]w[2mp] + i s[2mp+1]w[2mp+1]
    float2 v[8];
    if (c > 0 && c < NCHUNK - 1) {
        // no reflection possible: q index = 256g + 2mp -> contiguous float2
        #pragma unroll
        for (int m = 0; m < 8; ++m) {
            int mp = t + 64 * m;
            float2 sv = sigwin2[128 * g + mp];
            float2 w2 = win2[mp];
            v[m] = make_float2(sv.x * w2.x, sv.y * w2.y);
        }
    } else {
        #pragma unroll
        for (int m = 0; m < 8; ++m) {
            int mp = t + 64 * m;
            int js = 2 * mp;
            float sv[2];
            #pragma unroll
            for (int h = 0; h < 2; ++h) {
                int pp = 1024 * c + 256 * g + js + h;
                int u = pp - PADW;
                if (u < 0) u = -u;
                else if (u >= LOUT) u = 2 * LOUT - 2 - u;
                sv[h] = sigwin[u + PADW - 1024 * c];
            }
            float2 w2 = win2[mp];
            v[m] = make_float2(sv[0] * w2.x, sv[1] * w2.y);
        }
    }
    __syncthreads();   // sigwin fully consumed; C may now overwrite its space
    // ---- forward FFT
    dft8(v, +1.f);
    twchain(v, gtwr[2 * t], gtwi[2 * t]);               // W_512^t
    #pragma unroll
    for (int m = 0; m < 8; ++m) Cb[PC(8 * t + m)] = v[m];
    r8_stage2(Cb, gtwr, gtwi, t, +1.f);
    // ---- forward stage s=64: Zp in registers, one LDS write-back (free)
    float2 Zp[8];
    #pragma unroll
    for (int m = 0; m < 8; ++m) Zp[m] = Cb[PC(t + 64 * m)];
    dft8(Zp, +1.f);
    #pragma unroll
    for (int m = 0; m < 8; ++m) Cb[PC(t + 64 * m)] = Zp[m];
    // ---- projection; mirror bins JIT from LDS; fast rcp/sqrt
    #pragma unroll
    for (int m = 0; m < 8; ++m) {
        int p = t + 64 * m, q = 512 - p;
        float2 Zq = Cb[PC(q & 511)];
        float Ar = 0.5f * (Zp[m].x + Zq.x), Ai = 0.5f * (Zp[m].y - Zq.y);
        float Br = 0.5f * (Zp[m].x - Zq.x), Bi = 0.5f * (Zp[m].y + Zq.y);
        float Wr = gtwr[p & 511], Wi = gtwi[p & 511];
        float P = Wr * Bi + Wi * Br, Q = Wr * Br - Wi * Bi;
        float Xpr = Ar + P, Xpi = Ai - Q;
        float Xqr = Ar - P, Xqi = -Ai - Q;
        float scp = mrow[p] * __builtin_amdgcn_rcpf(
            __builtin_amdgcn_sqrtf(Xpr * Xpr + Xpi * Xpi) + 1e-8f);
        float scq = mrow[q & 1023] * __builtin_amdgcn_rcpf(
            __builtin_amdgcn_sqrtf(Xqr * Xqr + Xqi * Xqi) + 1e-8f);
        float ppr = Xpr * scp, ppi = Xpi * scp;
        float pqr = Xqr * scq, pqi = Xqi * scq;
        float Cr = 0.5f * (ppr + pqr), Ci = 0.5f * (ppi - pqi);
        float Dr = 0.5f * (ppr - pqr), Di = 0.5f * (ppi + pqi);
        float U = Wr * Di - Wi * Dr, V = Wr * Dr + Wi * Di;
        v[m] = make_float2(Cr - U, Ci + V);
    }
    if (t == 0) {
        float2 Z0 = Zp[0];
        float X0 = Z0.x + Z0.y, X512 = Z0.x - Z0.y;
        float p0   = mrow[0]   * X0   * __builtin_amdgcn_rcpf(fabsf(X0)   + 1e-8f);
        float p512 = mrow[512] * X512 * __builtin_amdgcn_rcpf(fabsf(X512) + 1e-8f);
        v[0] = make_float2(0.5f * (p0 + p512), 0.5f * (p0 - p512));
        float2 Zc = Zp[4];
        float X256r = Zc.x, X256i = -Zc.y;
        float sc = mrow[256] * __builtin_amdgcn_rcpf(
            __builtin_amdgcn_sqrtf(X256r * X256r + X256i * X256i) + 1e-8f);
        v[4] = make_float2(X256r * sc, -(X256i * sc));
    }
    // ---- inverse FFT; stage-1 consumes projection registers directly
    dft8(v, -1.f);
    twchain(v, gtwr[2 * t], -gtwi[2 * t]);              // conj for inverse
    #pragma unroll
    for (int m = 0; m < 8; ++m) Cb[PC(8 * t + m)] = v[m];
    r8_stage2(Cb, gtwr, gtwi, t, -1.f);
    // inverse stage s=64 (twiddle-free, in-place; conflict-free pattern)
    {
        float2 u[8];
        #pragma unroll
        for (int m = 0; m < 8; ++m) u[m] = Cb[PC(t + 64 * m)];
        dft8(u, -1.f);
        #pragma unroll
        for (int m = 0; m < 8; ++m) Cb[PC(t + 64 * m)] = u[m];
    }
    __syncthreads();
    // ---- intra-block OLA of 4 frames -> Pout[c]  (x[2m]=re, x[2m+1]=im)
    const float SC = 1.0f / 512.0f;
    float* Po = Pout + ((size_t)b * NCHUNK + c) * CSPAN;
    for (int j = tid; j < CSPAN; j += 256) {
        float acc = 0.f;
        #pragma unroll
        for (int gg = 0; gg < CHUNKF; ++gg) {
            int p = j - 256 * gg;
            if (p >= 0 && p < NFFT) {
                float2 zz = C[gg][PC(p >> 1)];
                float yv = (p & 1) ? zz.y : zz.x;
                acc += yv * win[p];
            }
        }
        Po[j] = acc * SC;
    }
}

// -------------------- final output (verified round 6)
__global__ void k_out(const float* __restrict__ P, const float* __restrict__ envinv,
                      float* __restrict__ out) {
    int i = blockIdx.x * 256 + threadIdx.x;
    int b = blockIdx.y;
    if (i >= LOUT) return;
    int ii = i + PADW;
    int c = ii >> 10; if (c > NCHUNK - 1) c = NCHUNK - 1;
    const float* Pb = P + (size_t)b * NCHUNK * CSPAN;
    int j = ii - 1024 * c;
    float v = Pb[c * CSPAN + j];
    if (c > 0) {
        int j2 = j + 1024;
        if (j2 < CSPAN) v += Pb[(c - 1) * CSPAN + j2];
    }
    out[(size_t)b * LOUT + i] = v * envinv[ii];
}

// ---------------------------------------------------------------------- host
extern "C" void kernel_launch(void* const* d_in, const int* in_sizes, int n_in,
                              void* d_out, int out_size, void* d_ws, size_t ws_size,
                              hipStream_t stream) {
    const float* mel = (const float*)d_in[0];   // (8, 80, 1024)
    const float* ang = (const float*)d_in[1];   // (8, 513, 1024)
    const float* fb  = (const float*)d_in[2];   // (513, 80)
    float* ws = (float*)d_ws;

    float* twr    = ws;                                   // 512   (W_1024)
    float* twi    = twr + NHALF;                          // 512
    float* t5r    = twi + NHALF;                          // 128   (W_512, init)
    float* t5i    = t5r + 128;                            // 128
    float* win    = t5i + 128;                            // 1024
    float* fbT    = win + NFFT;                           // 80*513
    float* envinv = fbT + NMELS * NFREQ;                  // LPAD
    float* mag    = envinv + LPAD;                        // 8*1024*513
    float* PA     = mag + (size_t)BATCH * TFRAMES * NFREQ;    // 8*256*1792
    float* PB     = PA + (size_t)BATCH * NCHUNK * CSPAN;      // 8*256*1792
    float* out    = (float*)d_out;

    k_init_tables<<<4, 256, 0, stream>>>(twr, twi, t5r, t5i, win);
    k_env<<<(LPAD + 255) / 256, 256, 0, stream>>>(win, envinv);
    k_fbt<<<(NFREQ * NMELS + 255) / 256, 256, 0, stream>>>(fb, fbT);
    {
        dim3 g(TFRAMES / 16, BATCH);
        k_mag<<<g, 256, 0, stream>>>(mel, fbT, mag);
    }
    k_init4<<<BATCH * NCHUNK, 512, 0, stream>>>(mag, ang, twr, twi, t5r, t5i, win, PA);

    float* fin = PA;
    float* fout = PB;
    for (int it = 0; it < NITER; ++it) {
        k_gl8<<<BATCH * NCHUNK, 256, 0, stream>>>(fin, mag, envinv, twr, twi,
                                                  win, fout);
        float* tmp = fin; fin = fout; fout = tmp;
    }
    dim3 og((LOUT + 255) / 256, BATCH);
    k_out<<<og, 256, 0, stream>>>(fin, envinv, out);
}

// Round 13
// 2043.461 us; speedup vs baseline: 1.0242x; 1.0242x over previous
//
#include <hip/hip_runtime.h>
#include <math.h>

#define NFFT   1024
#define NHALF  512
#define HOPSZ  256
#define NMELS  80
#define NFREQ  513
#define BATCH  8
#define TFRAMES 1024
#define PADW   512
#define LPAD   (NFFT + (TFRAMES - 1) * HOPSZ)   // 262912
#define LOUT   (LPAD - 2 * PADW)                // 261888
#define NITER  60
#define PI_D   3.14159265358979323846

#define CHUNKF 4                                // frames per chunk
#define CSPAN  1792                             // 1024 + 3*256
#define NCHUNK (TFRAMES / CHUNKF)               // 256

// padding for the (old, init-only) radix-4 FFT
#define PAD(p) ((p) + ((p) >> 5))
#define NPAD   (NHALF + (NHALF >> 5))           // 528

// padding for the hot-loop radix-8 C buffer (float2 units): +1 per 8
#define PC(p)  ((p) + ((p) >> 3))
#define C_SZ   576                              // PC(511)=574 < 576

// ---------------------------------------------------------------- init tables
__global__ void k_init_tables(float* __restrict__ twr, float* __restrict__ twi,
                              float* __restrict__ t5r, float* __restrict__ t5i,
                              float* __restrict__ win) {
    int j = blockIdx.x * 256 + threadIdx.x;
    if (j < NHALF) {
        double th = -2.0 * PI_D * (double)j / (double)NFFT;
        twr[j] = (float)cos(th);
        twi[j] = (float)sin(th);
    }
    if (j < 128) {
        double th = -2.0 * PI_D * (double)j / 512.0;
        t5r[j] = (float)cos(th);
        t5i[j] = (float)sin(th);
    }
    if (j < NFFT) {
        win[j] = (float)(0.5 - 0.5 * cos(2.0 * PI_D * (double)j / (double)NFFT));
    }
}

__global__ void k_env(const float* __restrict__ win, float* __restrict__ envinv) {
    int i = blockIdx.x * 256 + threadIdx.x;
    if (i >= LPAD) return;
    int thi = i / HOPSZ; if (thi > TFRAMES - 1) thi = TFRAMES - 1;
    int d = i - (NFFT - 1);
    int tlo = (d > 0) ? (d + HOPSZ - 1) / HOPSZ : 0;
    float e = 0.f;
    for (int t = tlo; t <= thi; ++t) { float w = win[i - t * HOPSZ]; e += w * w; }
    envinv[i] = (e > 1e-11f) ? (1.0f / e) : 1.0f;
}

__global__ void k_fbt(const float* __restrict__ fb, float* __restrict__ fbT) {
    int i = blockIdx.x * 256 + threadIdx.x;
    if (i < NFREQ * NMELS) {
        int k = i / NMELS, m = i - k * NMELS;
        fbT[m * NFREQ + k] = fb[i];
    }
}

// mag[(b*1024+t)*513+k], tiled 16 t per block
__global__ __launch_bounds__(256) void k_mag(const float* __restrict__ mel,
                                             const float* __restrict__ fbT,
                                             float* __restrict__ mag) {
    __shared__ float sm[NMELS * 16];
    int b = blockIdx.y, t0 = blockIdx.x * 16, tid = threadIdx.x;
    for (int idx = tid; idx < NMELS * 16; idx += 256) {
        int m = idx >> 4, tt = idx & 15;
        sm[idx] = expf(mel[(size_t)(b * NMELS + m) * TFRAMES + (t0 + tt)]);
    }
    __syncthreads();
    for (int k = tid; k < NFREQ; k += 256) {
        float acc[16];
        #pragma unroll
        for (int tt = 0; tt < 16; ++tt) acc[tt] = 0.f;
        for (int m = 0; m < NMELS; ++m) {
            float w = fbT[m * NFREQ + k];
            #pragma unroll
            for (int tt = 0; tt < 16; ++tt) acc[tt] += w * sm[m * 16 + tt];
        }
        #pragma unroll
        for (int tt = 0; tt < 16; ++tt)
            mag[(size_t)((b << 10) + t0 + tt) * NFREQ + k] = fmaxf(acc[tt], 0.f);
    }
}

// ===================== old radix-4 path (init kernel only, verified round 6)
__device__ __forceinline__ void fft512_m(float* xr, float* xi, float* yr, float* yi,
                                         const float* t5r, const float* t5i,
                                         int l, float sgn) {
    float *ar = xr, *ai = xi, *br = yr, *bi = yi;
    #pragma unroll
    for (int st = 0; st < 4; ++st) {
        int s = 1 << (2 * st);
        __syncthreads();
        int j = l;
        int hi = j & ~(s - 1);
        int o1 = j + 3 * hi;
        float v0r = ar[PAD(j)],       v0i = ai[PAD(j)];
        float v1r = ar[PAD(j + 128)], v1i = ai[PAD(j + 128)];
        float v2r = ar[PAD(j + 256)], v2i = ai[PAD(j + 256)];
        float v3r = ar[PAD(j + 384)], v3i = ai[PAD(j + 384)];
        float a_r = v0r + v2r, a_i = v0i + v2i;
        float b_r = v0r - v2r, b_i = v0i - v2i;
        float c_r = v1r + v3r, c_i = v1i + v3i;
        float d_r = v1r - v3r, d_i = v1i - v3i;
        float X0r = a_r + c_r, X0i = a_i + c_i;
        float X2r = a_r - c_r, X2i = a_i - c_i;
        float X1r = b_r + sgn * d_i, X1i = b_i - sgn * d_r;
        float X3r = b_r - sgn * d_i, X3i = b_i + sgn * d_r;
        float w1r = t5r[hi], w1i = sgn * t5i[hi];
        float w2r = w1r * w1r - w1i * w1i, w2i = 2.f * w1r * w1i;
        float w3r = w2r * w1r - w2i * w1i, w3i = w2r * w1i + w2i * w1r;
        br[PAD(o1)]         = X0r;
        bi[PAD(o1)]         = X0i;
        br[PAD(o1 + s)]     = X1r * w1r - X1i * w1i;
        bi[PAD(o1 + s)]     = X1r * w1i + X1i * w1r;
        br[PAD(o1 + 2*s)]   = X2r * w2r - X2i * w2i;
        bi[PAD(o1 + 2*s)]   = X2r * w2i + X2i * w2r;
        br[PAD(o1 + 3*s)]   = X3r * w3r - X3i * w3i;
        bi[PAD(o1 + 3*s)]   = X3r * w3i + X3i * w3r;
        float* t0 = ar; ar = br; br = t0;
        float* t1 = ai; ai = bi; bi = t1;
    }
    __syncthreads();
    #pragma unroll
    for (int r = 0; r < 2; ++r) {
        int j = l + r * 128;
        float x0r = ar[PAD(j)],       x0i = ai[PAD(j)];
        float x1r = ar[PAD(j + 256)], x1i = ai[PAD(j + 256)];
        br[PAD(j)]       = x0r + x1r;
        bi[PAD(j)]       = x0i + x1i;
        br[PAD(j + 256)] = x0r - x1r;
        bi[PAD(j + 256)] = x0i - x1i;
    }
}

__device__ __forceinline__ void chunk_ola4(float (*Yr)[NPAD], float (*Yi)[NPAD],
                                           const float* swin, float* Po, int tid) {
    const float SC = 1.0f / 512.0f;
    for (int j = tid; j < CSPAN; j += 512) {
        float acc = 0.f;
        #pragma unroll
        for (int gg = 0; gg < CHUNKF; ++gg) {
            int p = j - 256 * gg;
            if (p >= 0 && p < NFFT) {
                float yv = (p & 1) ? Yi[gg][PAD(p >> 1)] : Yr[gg][PAD(p >> 1)];
                acc += yv * swin[p];
            }
        }
        Po[j] = acc * SC;
    }
}

// -------------------- init: P0 from mag * e^{i 2pi ang} (verified round 6)
__global__ __launch_bounds__(512) void k_init4(
        const float* __restrict__ mag, const float* __restrict__ ang,
        const float* __restrict__ gtwr, const float* __restrict__ gtwi,
        const float* __restrict__ gt5r, const float* __restrict__ gt5i,
        const float* __restrict__ win, float* __restrict__ Pout) {
    __shared__ float swin[NFFT];
    __shared__ float Xr[CHUNKF][NPAD], Xi[CHUNKF][NPAD];
    __shared__ float Yr[CHUNKF][NPAD], Yi[CHUNKF][NPAD];
    __shared__ float t5r[128], t5i[128];
    int blk = blockIdx.x; int b = blk >> 8; int c = blk & (NCHUNK - 1);
    int tid = threadIdx.x; int g = tid >> 7; int l = tid & 127;
    if (tid < 128) { t5r[tid] = gt5r[tid]; t5i[tid] = gt5i[tid]; }
    for (int q = tid; q < NFFT; q += 512) swin[q] = win[q];
    int ft = CHUNKF * c + g;
    const float* mrow = mag + (size_t)(b * TFRAMES + ft) * NFREQ;
    const float TWO_PI = 6.283185307179586477f;
    if (l == 0) {
        float a0, s0, c0;
        a0 = ang[((size_t)(b * NFREQ + 0)) * TFRAMES + ft] * TWO_PI;
        sincosf(a0, &s0, &c0);
        float p0 = mrow[0] * c0;
        a0 = ang[((size_t)(b * NFREQ + 512)) * TFRAMES + ft] * TWO_PI;
        sincosf(a0, &s0, &c0);
        float p512 = mrow[512] * c0;
        Xr[g][PAD(0)] = 0.5f * (p0 + p512);
        Xi[g][PAD(0)] = 0.5f * (p0 - p512);
        a0 = ang[((size_t)(b * NFREQ + 256)) * TFRAMES + ft] * TWO_PI;
        sincosf(a0, &s0, &c0);
        Xr[g][PAD(256)] = mrow[256] * c0;
        Xi[g][PAD(256)] = -(mrow[256] * s0);
    }
    #pragma unroll
    for (int q2 = 0; q2 < 2; ++q2) {
        int k = l + q2 * 128;
        if (k == 0) continue;
        int j = 512 - k;
        float ak = ang[((size_t)(b * NFREQ + k)) * TFRAMES + ft] * TWO_PI;
        float aj = ang[((size_t)(b * NFREQ + j)) * TFRAMES + ft] * TWO_PI;
        float sk, ck, sj, cj;
        sincosf(ak, &sk, &ck); sincosf(aj, &sj, &cj);
        float pkr = mrow[k] * ck, pki = mrow[k] * sk;
        float pjr = mrow[j] * cj, pji = mrow[j] * sj;
        float Wr = gtwr[k], Wi = gtwi[k];
        float Cr = 0.5f * (pkr + pjr), Ci = 0.5f * (pki - pji);
        float Dr = 0.5f * (pkr - pjr), Di = 0.5f * (pki + pji);
        float U = Wr * Di - Wi * Dr, V = Wr * Dr + Wi * Di;
        Xr[g][PAD(k)] = Cr - U;  Xi[g][PAD(k)] = Ci + V;
        Xr[g][PAD(j)] = Cr + U;  Xi[g][PAD(j)] = -Ci + V;
    }
    fft512_m(Xr[g], Xi[g], Yr[g], Yi[g], t5r, t5i, l, -1.f);
    __syncthreads();
    chunk_ola4(Yr, Yi, swin, Pout + ((size_t)b * NCHUNK + c) * CSPAN, tid);
}

// ===================== wave-local radix-8 machinery (hot loop) ==============
__device__ __forceinline__ float2 cmul(float2 a, float2 b) {
    return make_float2(a.x * b.x - a.y * b.y, a.x * b.y + a.y * b.x);
}

// in-register 8-pt DFT; sgn=+1 forward, -1 inverse (verified round 7)
__device__ __forceinline__ void dft8(float2 v[8], float sgn) {
    const float s2 = 0.70710678118654752f;
    float ar = v[0].x + v[4].x, ai = v[0].y + v[4].y;
    float br = v[0].x - v[4].x, bi = v[0].y - v[4].y;
    float cr = v[2].x + v[6].x, ci = v[2].y + v[6].y;
    float dr = v[2].x - v[6].x, di = v[2].y - v[6].y;
    float2 E0 = make_float2(ar + cr, ai + ci);
    float2 E2 = make_float2(ar - cr, ai - ci);
    float2 E1 = make_float2(br + sgn * di, bi - sgn * dr);
    float2 E3 = make_float2(br - sgn * di, bi + sgn * dr);
    float ar2 = v[1].x + v[5].x, ai2 = v[1].y + v[5].y;
    float br2 = v[1].x - v[5].x, bi2 = v[1].y - v[5].y;
    float cr2 = v[3].x + v[7].x, ci2 = v[3].y + v[7].y;
    float dr2 = v[3].x - v[7].x, di2 = v[3].y - v[7].y;
    float2 O0 = make_float2(ar2 + cr2, ai2 + ci2);
    float2 O2 = make_float2(ar2 - cr2, ai2 - ci2);
    float2 O1 = make_float2(br2 + sgn * di2, bi2 - sgn * dr2);
    float2 O3 = make_float2(br2 - sgn * di2, bi2 + sgn * dr2);
    float2 T1 = make_float2((O1.x + sgn * O1.y) * s2, (O1.y - sgn * O1.x) * s2);
    float2 T2 = make_float2(sgn * O2.y, -sgn * O2.x);
    float2 T3 = make_float2((-O3.x + sgn * O3.y) * s2, (-O3.y - sgn * O3.x) * s2);
    v[0] = make_float2(E0.x + O0.x, E0.y + O0.y);
    v[4] = make_float2(E0.x - O0.x, E0.y - O0.y);
    v[1] = make_float2(E1.x + T1.x, E1.y + T1.y);
    v[5] = make_float2(E1.x - T1.x, E1.y - T1.y);
    v[2] = make_float2(E2.x + T2.x, E2.y + T2.y);
    v[6] = make_float2(E2.x - T2.x, E2.y - T2.y);
    v[3] = make_float2(E3.x + T3.x, E3.y + T3.y);
    v[7] = make_float2(E3.x - T3.x, E3.y - T3.y);
}

// apply v[m] *= W^m for m=1..7, W=(wr,wi)  (low-register sequential chain)
__device__ __forceinline__ void twchain(float2 v[8], float wr, float wi) {
    float2 w = make_float2(wr, wi), cur = w;
    #pragma unroll
    for (int m = 1; m < 8; ++m) { v[m] = cmul(v[m], cur); cur = cmul(cur, w); }
}

// stage s=8: read Cb[t+64m] (free), dft8, twiddle, write Cb[64a+r+8m] (4-way)
__device__ __forceinline__ void r8_stage2(float2* Cb, const float* gtwr,
                                          const float* gtwi, int t, float sgn) {
    float2 u[8];
    #pragma unroll
    for (int m = 0; m < 8; ++m) u[m] = Cb[PC(t + 64 * m)];
    dft8(u, sgn);
    int a = t >> 3;
    twchain(u, gtwr[16 * a], sgn * gtwi[16 * a]);      // W_64^a = W_1024^{16a}
    int o1 = 64 * a + (t & 7);
    #pragma unroll
    for (int m = 0; m < 8; ++m) Cb[PC(o1 + 8 * m)] = u[m];
}

// -------- hot GL iteration: 18432 B LDS (8 blocks/CU, no residency tail);
// synthesis window*SC folded into inverse-FFT writeback (coalesced float2
// global win reads, L1-hit) so the OLA loop is pure LDS add — fixes round 12's
// 28-scalar-global-win-loads regression while keeping round 12's occupancy.
__global__ __launch_bounds__(256, 4) void k_gl8(
        const float* __restrict__ Pin, const float* __restrict__ mag,
        const float* __restrict__ envinv,
        const float* __restrict__ gtwr, const float* __restrict__ gtwi,
        const float* __restrict__ win, float* __restrict__ Pout) {
    __shared__ __align__(16) unsigned char smem_raw[CHUNKF * C_SZ * sizeof(float2)];
    float2 (*C)[C_SZ] = reinterpret_cast<float2(*)[C_SZ]>(smem_raw);
    float*  sigwin  = reinterpret_cast<float*>(smem_raw);   // first 7168 B of C
    float2* sigwin2 = reinterpret_cast<float2*>(smem_raw);
    int blk = blockIdx.x; int b = blk >> 8; int c = blk & (NCHUNK - 1);
    int tid = threadIdx.x; int g = tid >> 6; int t = tid & 63;
    // ---- stage normalized signal window (identical to verified round 6)
    const float* Pb = Pin + (size_t)b * NCHUNK * CSPAN;
    for (int q = tid; q < CSPAN; q += 256) {
        float v = Pb[c * CSPAN + q];
        if (q < 768 && c > 0)              v += Pb[(c - 1) * CSPAN + q + 1024];
        if (q >= 1024 && c < NCHUNK - 1)   v += Pb[(c + 1) * CSPAN + q - 1024];
        sigwin[q] = v * envinv[1024 * c + q];
    }
    __syncthreads();
    float2* Cb = C[g];
    const float2* win2 = (const float2*)win;       // global, L1-resident
    int ft = CHUNKF * c + g;
    const float* mrow = mag + (size_t)(b * TFRAMES + ft) * NFREQ;
    // ---- z-pack into registers: z[m] = s[2mp]w[2mp] + i s[2mp+1]w[2mp+1]
    float2 v[8];
    if (c > 0 && c < NCHUNK - 1) {
        // no reflection possible: q index = 256g + 2mp -> contiguous float2
        #pragma unroll
        for (int m = 0; m < 8; ++m) {
            int mp = t + 64 * m;
            float2 sv = sigwin2[128 * g + mp];
            float2 w2 = win2[mp];
            v[m] = make_float2(sv.x * w2.x, sv.y * w2.y);
        }
    } else {
        #pragma unroll
        for (int m = 0; m < 8; ++m) {
            int mp = t + 64 * m;
            int js = 2 * mp;
            float sv[2];
            #pragma unroll
            for (int h = 0; h < 2; ++h) {
                int pp = 1024 * c + 256 * g + js + h;
                int u = pp - PADW;
                if (u < 0) u = -u;
                else if (u >= LOUT) u = 2 * LOUT - 2 - u;
                sv[h] = sigwin[u + PADW - 1024 * c];
            }
            float2 w2 = win2[mp];
            v[m] = make_float2(sv[0] * w2.x, sv[1] * w2.y);
        }
    }
    __syncthreads();   // sigwin fully consumed; C may now overwrite its space
    // ---- forward FFT
    dft8(v, +1.f);
    twchain(v, gtwr[2 * t], gtwi[2 * t]);               // W_512^t
    #pragma unroll
    for (int m = 0; m < 8; ++m) Cb[PC(8 * t + m)] = v[m];
    r8_stage2(Cb, gtwr, gtwi, t, +1.f);
    // ---- forward stage s=64: Zp in registers, one LDS write-back (free)
    float2 Zp[8];
    #pragma unroll
    for (int m = 0; m < 8; ++m) Zp[m] = Cb[PC(t + 64 * m)];
    dft8(Zp, +1.f);
    #pragma unroll
    for (int m = 0; m < 8; ++m) Cb[PC(t + 64 * m)] = Zp[m];
    // ---- projection; mirror bins JIT from LDS; fast rcp/sqrt
    #pragma unroll
    for (int m = 0; m < 8; ++m) {
        int p = t + 64 * m, q = 512 - p;
        float2 Zq = Cb[PC(q & 511)];
        float Ar = 0.5f * (Zp[m].x + Zq.x), Ai = 0.5f * (Zp[m].y - Zq.y);
        float Br = 0.5f * (Zp[m].x - Zq.x), Bi = 0.5f * (Zp[m].y + Zq.y);
        float Wr = gtwr[p & 511], Wi = gtwi[p & 511];
        float P = Wr * Bi + Wi * Br, Q = Wr * Br - Wi * Bi;
        float Xpr = Ar + P, Xpi = Ai - Q;
        float Xqr = Ar - P, Xqi = -Ai - Q;
        float scp = mrow[p] * __builtin_amdgcn_rcpf(
            __builtin_amdgcn_sqrtf(Xpr * Xpr + Xpi * Xpi) + 1e-8f);
        float scq = mrow[q & 1023] * __builtin_amdgcn_rcpf(
            __builtin_amdgcn_sqrtf(Xqr * Xqr + Xqi * Xqi) + 1e-8f);
        float ppr = Xpr * scp, ppi = Xpi * scp;
        float pqr = Xqr * scq, pqi = Xqi * scq;
        float Cr = 0.5f * (ppr + pqr), Ci = 0.5f * (ppi - pqi);
        float Dr = 0.5f * (ppr - pqr), Di = 0.5f * (ppi + pqi);
        float U = Wr * Di - Wi * Dr, V = Wr * Dr + Wi * Di;
        v[m] = make_float2(Cr - U, Ci + V);
    }
    if (t == 0) {
        float2 Z0 = Zp[0];
        float X0 = Z0.x + Z0.y, X512 = Z0.x - Z0.y;
        float p0   = mrow[0]   * X0   * __builtin_amdgcn_rcpf(fabsf(X0)   + 1e-8f);
        float p512 = mrow[512] * X512 * __builtin_amdgcn_rcpf(fabsf(X512) + 1e-8f);
        v[0] = make_float2(0.5f * (p0 + p512), 0.5f * (p0 - p512));
        float2 Zc = Zp[4];
        float X256r = Zc.x, X256i = -Zc.y;
        float sc = mrow[256] * __builtin_amdgcn_rcpf(
            __builtin_amdgcn_sqrtf(X256r * X256r + X256i * X256i) + 1e-8f);
        v[4] = make_float2(X256r * sc, -(X256i * sc));
    }
    // ---- inverse FFT; stage-1 consumes projection registers directly
    dft8(v, -1.f);
    twchain(v, gtwr[2 * t], -gtwi[2 * t]);              // conj for inverse
    #pragma unroll
    for (int m = 0; m < 8; ++m) Cb[PC(8 * t + m)] = v[m];
    r8_stage2(Cb, gtwr, gtwi, t, -1.f);
    // inverse stage s=64: apply synthesis window * (1/512) in registers at
    // writeback — u[m] holds samples x[2(t+64m)], x[2(t+64m)+1] = win2[t+64m]
    {
        const float SC = 1.0f / 512.0f;
        float2 u[8];
        #pragma unroll
        for (int m = 0; m < 8; ++m) u[m] = Cb[PC(t + 64 * m)];
        dft8(u, -1.f);
        #pragma unroll
        for (int m = 0; m < 8; ++m) {
            float2 w2 = win2[t + 64 * m];
            Cb[PC(t + 64 * m)] = make_float2(u[m].x * w2.x * SC,
                                             u[m].y * w2.y * SC);
        }
    }
    __syncthreads();
    // ---- intra-block OLA of 4 frames -> Pout[c]  (pure LDS add; window
    //      and scale already applied in the writeback above)
    float* Po = Pout + ((size_t)b * NCHUNK + c) * CSPAN;
    for (int j = tid; j < CSPAN; j += 256) {
        float acc = 0.f;
        #pragma unroll
        for (int gg = 0; gg < CHUNKF; ++gg) {
            int p = j - 256 * gg;
            if (p >= 0 && p < NFFT) {
                float2 zz = C[gg][PC(p >> 1)];
                acc += (p & 1) ? zz.y : zz.x;
            }
        }
        Po[j] = acc;
    }
}

// -------------------- final output (verified round 6)
__global__ void k_out(const float* __restrict__ P, const float* __restrict__ envinv,
                      float* __restrict__ out) {
    int i = blockIdx.x * 256 + threadIdx.x;
    int b = blockIdx.y;
    if (i >= LOUT) return;
    int ii = i + PADW;
    int c = ii >> 10; if (c > NCHUNK - 1) c = NCHUNK - 1;
    const float* Pb = P + (size_t)b * NCHUNK * CSPAN;
    int j = ii - 1024 * c;
    float v = Pb[c * CSPAN + j];
    if (c > 0) {
        int j2 = j + 1024;
        if (j2 < CSPAN) v += Pb[(c - 1) * CSPAN + j2];
    }
    out[(size_t)b * LOUT + i] = v * envinv[ii];
}

// ---------------------------------------------------------------------- host
extern "C" void kernel_launch(void* const* d_in, const int* in_sizes, int n_in,
                              void* d_out, int out_size, void* d_ws, size_t ws_size,
                              hipStream_t stream) {
    const float* mel = (const float*)d_in[0];   // (8, 80, 1024)
    const float* ang = (const float*)d_in[1];   // (8, 513, 1024)
    const float* fb  = (const float*)d_in[2];   // (513, 80)
    float* ws = (float*)d_ws;

    float* twr    = ws;                                   // 512   (W_1024)
    float* twi    = twr + NHALF;                          // 512
    float* t5r    = twi + NHALF;                          // 128   (W_512, init)
    float* t5i    = t5r + 128;                            // 128
    float* win    = t5i + 128;                            // 1024
    float* fbT    = win + NFFT;                           // 80*513
    float* envinv = fbT + NMELS * NFREQ;                  // LPAD
    float* mag    = envinv + LPAD;                        // 8*1024*513
    float* PA     = mag + (size_t)BATCH * TFRAMES * NFREQ;    // 8*256*1792
    float* PB     = PA + (size_t)BATCH * NCHUNK * CSPAN;      // 8*256*1792
    float* out    = (float*)d_out;

    k_init_tables<<<4, 256, 0, stream>>>(twr, twi, t5r, t5i, win);
    k_env<<<(LPAD + 255) / 256, 256, 0, stream>>>(win, envinv);
    k_fbt<<<(NFREQ * NMELS + 255) / 256, 256, 0, stream>>>(fb, fbT);
    {
        dim3 g(TFRAMES / 16, BATCH);
        k_mag<<<g, 256, 0, stream>>>(mel, fbT, mag);
    }
    k_init4<<<BATCH * NCHUNK, 512, 0, stream>>>(mag, ang, twr, twi, t5r, t5i, win, PA);

    float* fin = PA;
    float* fout = PB;
    for (int it = 0; it < NITER; ++it) {
        k_gl8<<<BATCH * NCHUNK, 256, 0, stream>>>(fin, mag, envinv, twr, twi,
                                                  win, fout);
        float* tmp = fin; fin = fout; fout = tmp;
    }
    dim3 og((LOUT + 255) / 256, BATCH);
    k_out<<<og, 256, 0, stream>>>(fin, envinv, out);
}

// Round 15
// 1927.947 us; speedup vs baseline: 1.0855x; 1.0599x over previous
//
#include <hip/hip_runtime.h>
#include <math.h>

#define NFFT   1024
#define NHALF  512
#define HOPSZ  256
#define NMELS  80
#define NFREQ  513
#define BATCH  8
#define TFRAMES 1024
#define PADW   512
#define LPAD   (NFFT + (TFRAMES - 1) * HOPSZ)   // 262912
#define LOUT   (LPAD - 2 * PADW)                // 261888
#define NITER  60
#define PI_D   3.14159265358979323846

#define CHUNKF 4                                // frames per chunk
#define CSPAN  1792                             // 1024 + 3*256
#define NCHUNK (TFRAMES / CHUNKF)               // 256

// padding for the (old, init-only) radix-4 FFT
#define PAD(p) ((p) + ((p) >> 5))
#define NPAD   (NHALF + (NHALF >> 5))           // 528

// padding for the hot-loop radix-8 C buffer (float2 units): +1 per 8
// max used index PC(511)=574 -> 575 entries suffice (frees 32 B for wtab)
#define PC(p)  ((p) + ((p) >> 3))
#define C_SZ   575

// ---------------------------------------------------------------- init tables
__global__ void k_init_tables(float* __restrict__ twr, float* __restrict__ twi,
                              float* __restrict__ t5r, float* __restrict__ t5i,
                              float* __restrict__ win) {
    int j = blockIdx.x * 256 + threadIdx.x;
    if (j < NHALF) {
        double th = -2.0 * PI_D * (double)j / (double)NFFT;
        twr[j] = (float)cos(th);
        twi[j] = (float)sin(th);
    }
    if (j < 128) {
        double th = -2.0 * PI_D * (double)j / 512.0;
        t5r[j] = (float)cos(th);
        t5i[j] = (float)sin(th);
    }
    if (j < NFFT) {
        win[j] = (float)(0.5 - 0.5 * cos(2.0 * PI_D * (double)j / (double)NFFT));
    }
}

__global__ void k_env(const float* __restrict__ win, float* __restrict__ envinv) {
    int i = blockIdx.x * 256 + threadIdx.x;
    if (i >= LPAD) return;
    int thi = i / HOPSZ; if (thi > TFRAMES - 1) thi = TFRAMES - 1;
    int d = i - (NFFT - 1);
    int tlo = (d > 0) ? (d + HOPSZ - 1) / HOPSZ : 0;
    float e = 0.f;
    for (int t = tlo; t <= thi; ++t) { float w = win[i - t * HOPSZ]; e += w * w; }
    envinv[i] = (e > 1e-11f) ? (1.0f / e) : 1.0f;
}

__global__ void k_fbt(const float* __restrict__ fb, float* __restrict__ fbT) {
    int i = blockIdx.x * 256 + threadIdx.x;
    if (i < NFREQ * NMELS) {
        int k = i / NMELS, m = i - k * NMELS;
        fbT[m * NFREQ + k] = fb[i];
    }
}

// mag[(b*1024+t)*513+k], tiled 16 t per block
__global__ __launch_bounds__(256) void k_mag(const float* __restrict__ mel,
                                             const float* __restrict__ fbT,
                                             float* __restrict__ mag) {
    __shared__ float sm[NMELS * 16];
    int b = blockIdx.y, t0 = blockIdx.x * 16, tid = threadIdx.x;
    for (int idx = tid; idx < NMELS * 16; idx += 256) {
        int m = idx >> 4, tt = idx & 15;
        sm[idx] = expf(mel[(size_t)(b * NMELS + m) * TFRAMES + (t0 + tt)]);
    }
    __syncthreads();
    for (int k = tid; k < NFREQ; k += 256) {
        float acc[16];
        #pragma unroll
        for (int tt = 0; tt < 16; ++tt) acc[tt] = 0.f;
        for (int m = 0; m < NMELS; ++m) {
            float w = fbT[m * NFREQ + k];
            #pragma unroll
            for (int tt = 0; tt < 16; ++tt) acc[tt] += w * sm[m * 16 + tt];
        }
        #pragma unroll
        for (int tt = 0; tt < 16; ++tt)
            mag[(size_t)((b << 10) + t0 + tt) * NFREQ + k] = fmaxf(acc[tt], 0.f);
    }
}

// ===================== old radix-4 path (init kernel only, verified round 6)
__device__ __forceinline__ void fft512_m(float* xr, float* xi, float* yr, float* yi,
                                         const float* t5r, const float* t5i,
                                         int l, float sgn) {
    float *ar = xr, *ai = xi, *br = yr, *bi = yi;
    #pragma unroll
    for (int st = 0; st < 4; ++st) {
        int s = 1 << (2 * st);
        __syncthreads();
        int j = l;
        int hi = j & ~(s - 1);
        int o1 = j + 3 * hi;
        float v0r = ar[PAD(j)],       v0i = ai[PAD(j)];
        float v1r = ar[PAD(j + 128)], v1i = ai[PAD(j + 128)];
        float v2r = ar[PAD(j + 256)], v2i = ai[PAD(j + 256)];
        float v3r = ar[PAD(j + 384)], v3i = ai[PAD(j + 384)];
        float a_r = v0r + v2r, a_i = v0i + v2i;
        float b_r = v0r - v2r, b_i = v0i - v2i;
        float c_r = v1r + v3r, c_i = v1i + v3i;
        float d_r = v1r - v3r, d_i = v1i - v3i;
        float X0r = a_r + c_r, X0i = a_i + c_i;
        float X2r = a_r - c_r, X2i = a_i - c_i;
        float X1r = b_r + sgn * d_i, X1i = b_i - sgn * d_r;
        float X3r = b_r - sgn * d_i, X3i = b_i + sgn * d_r;
        float w1r = t5r[hi], w1i = sgn * t5i[hi];
        float w2r = w1r * w1r - w1i * w1i, w2i = 2.f * w1r * w1i;
        float w3r = w2r * w1r - w2i * w1i, w3i = w2r * w1i + w2i * w1r;
        br[PAD(o1)]         = X0r;
        bi[PAD(o1)]         = X0i;
        br[PAD(o1 + s)]     = X1r * w1r - X1i * w1i;
        bi[PAD(o1 + s)]     = X1r * w1i + X1i * w1r;
        br[PAD(o1 + 2*s)]   = X2r * w2r - X2i * w2i;
        bi[PAD(o1 + 2*s)]   = X2r * w2i + X2i * w2r;
        br[PAD(o1 + 3*s)]   = X3r * w3r - X3i * w3i;
        bi[PAD(o1 + 3*s)]   = X3r * w3i + X3i * w3r;
        float* t0 = ar; ar = br; br = t0;
        float* t1 = ai; ai = bi; bi = t1;
    }
    __syncthreads();
    #pragma unroll
    for (int r = 0; r < 2; ++r) {
        int j = l + r * 128;
        float x0r = ar[PAD(j)],       x0i = ai[PAD(j)];
        float x1r = ar[PAD(j + 256)], x1i = ai[PAD(j + 256)];
        br[PAD(j)]       = x0r + x1r;
        bi[PAD(j)]       = x0i + x1i;
        br[PAD(j + 256)] = x0r - x1r;
        bi[PAD(j + 256)] = x0i - x1i;
    }
}

__device__ __forceinline__ void chunk_ola4(float (*Yr)[NPAD], float (*Yi)[NPAD],
                                           const float* swin, float* Po, int tid) {
    const float SC = 1.0f / 512.0f;
    for (int j = tid; j < CSPAN; j += 512) {
        float acc = 0.f;
        #pragma unroll
        for (int gg = 0; gg < CHUNKF; ++gg) {
            int p = j - 256 * gg;
            if (p >= 0 && p < NFFT) {
                float yv = (p & 1) ? Yi[gg][PAD(p >> 1)] : Yr[gg][PAD(p >> 1)];
                acc += yv * swin[p];
            }
        }
        Po[j] = acc * SC;
    }
}

// -------------------- init: P0 from mag * e^{i 2pi ang} (verified round 6)
__global__ __launch_bounds__(512) void k_init4(
        const float* __restrict__ mag, const float* __restrict__ ang,
        const float* __restrict__ gtwr, const float* __restrict__ gtwi,
        const float* __restrict__ gt5r, const float* __restrict__ gt5i,
        const float* __restrict__ win, float* __restrict__ Pout) {
    __shared__ float swin[NFFT];
    __shared__ float Xr[CHUNKF][NPAD], Xi[CHUNKF][NPAD];
    __shared__ float Yr[CHUNKF][NPAD], Yi[CHUNKF][NPAD];
    __shared__ float t5r[128], t5i[128];
    int blk = blockIdx.x; int b = blk >> 8; int c = blk & (NCHUNK - 1);
    int tid = threadIdx.x; int g = tid >> 7; int l = tid & 127;
    if (tid < 128) { t5r[tid] = gt5r[tid]; t5i[tid] = gt5i[tid]; }
    for (int q = tid; q < NFFT; q += 512) swin[q] = win[q];
    int ft = CHUNKF * c + g;
    const float* mrow = mag + (size_t)(b * TFRAMES + ft) * NFREQ;
    const float TWO_PI = 6.283185307179586477f;
    if (l == 0) {
        float a0, s0, c0;
        a0 = ang[((size_t)(b * NFREQ + 0)) * TFRAMES + ft] * TWO_PI;
        sincosf(a0, &s0, &c0);
        float p0 = mrow[0] * c0;
        a0 = ang[((size_t)(b * NFREQ + 512)) * TFRAMES + ft] * TWO_PI;
        sincosf(a0, &s0, &c0);
        float p512 = mrow[512] * c0;
        Xr[g][PAD(0)] = 0.5f * (p0 + p512);
        Xi[g][PAD(0)] = 0.5f * (p0 - p512);
        a0 = ang[((size_t)(b * NFREQ + 256)) * TFRAMES + ft] * TWO_PI;
        sincosf(a0, &s0, &c0);
        Xr[g][PAD(256)] = mrow[256] * c0;
        Xi[g][PAD(256)] = -(mrow[256] * s0);
    }
    #pragma unroll
    for (int q2 = 0; q2 < 2; ++q2) {
        int k = l + q2 * 128;
        if (k == 0) continue;
        int j = 512 - k;
        float ak = ang[((size_t)(b * NFREQ + k)) * TFRAMES + ft] * TWO_PI;
        float aj = ang[((size_t)(b * NFREQ + j)) * TFRAMES + ft] * TWO_PI;
        float sk, ck, sj, cj;
        sincosf(ak, &sk, &ck); sincosf(aj, &sj, &cj);
        float pkr = mrow[k] * ck, pki = mrow[k] * sk;
        float pjr = mrow[j] * cj, pji = mrow[j] * sj;
        float Wr = gtwr[k], Wi = gtwi[k];
        float Cr = 0.5f * (pkr + pjr), Ci = 0.5f * (pki - pji);
        float Dr = 0.5f * (pkr - pjr), Di = 0.5f * (pki + pji);
        float U = Wr * Di - Wi * Dr, V = Wr * Dr + Wi * Di;
        Xr[g][PAD(k)] = Cr - U;  Xi[g][PAD(k)] = Ci + V;
        Xr[g][PAD(j)] = Cr + U;  Xi[g][PAD(j)] = -Ci + V;
    }
    fft512_m(Xr[g], Xi[g], Yr[g], Yi[g], t5r, t5i, l, -1.f);
    __syncthreads();
    chunk_ola4(Yr, Yi, swin, Pout + ((size_t)b * NCHUNK + c) * CSPAN, tid);
}

// ===================== wave-local radix-8 machinery (hot loop) ==============
__device__ __forceinline__ float2 cmul(float2 a, float2 b) {
    return make_float2(a.x * b.x - a.y * b.y, a.x * b.y + a.y * b.x);
}

// in-register 8-pt DFT; sgn=+1 forward, -1 inverse (verified round 7)
__device__ __forceinline__ void dft8(float2 v[8], float sgn) {
    const float s2 = 0.70710678118654752f;
    float ar = v[0].x + v[4].x, ai = v[0].y + v[4].y;
    float br = v[0].x - v[4].x, bi = v[0].y - v[4].y;
    float cr = v[2].x + v[6].x, ci = v[2].y + v[6].y;
    float dr = v[2].x - v[6].x, di = v[2].y - v[6].y;
    float2 E0 = make_float2(ar + cr, ai + ci);
    float2 E2 = make_float2(ar - cr, ai - ci);
    float2 E1 = make_float2(br + sgn * di, bi - sgn * dr);
    float2 E3 = make_float2(br - sgn * di, bi + sgn * dr);
    float ar2 = v[1].x + v[5].x, ai2 = v[1].y + v[5].y;
    float br2 = v[1].x - v[5].x, bi2 = v[1].y - v[5].y;
    float cr2 = v[3].x + v[7].x, ci2 = v[3].y + v[7].y;
    float dr2 = v[3].x - v[7].x, di2 = v[3].y - v[7].y;
    float2 O0 = make_float2(ar2 + cr2, ai2 + ci2);
    float2 O2 = make_float2(ar2 - cr2, ai2 - ci2);
    float2 O1 = make_float2(br2 + sgn * di2, bi2 - sgn * dr2);
    float2 O3 = make_float2(br2 - sgn * di2, bi2 + sgn * dr2);
    float2 T1 = make_float2((O1.x + sgn * O1.y) * s2, (O1.y - sgn * O1.x) * s2);
    float2 T2 = make_float2(sgn * O2.y, -sgn * O2.x);
    float2 T3 = make_float2((-O3.x + sgn * O3.y) * s2, (-O3.y - sgn * O3.x) * s2);
    v[0] = make_float2(E0.x + O0.x, E0.y + O0.y);
    v[4] = make_float2(E0.x - O0.x, E0.y - O0.y);
    v[1] = make_float2(E1.x + T1.x, E1.y + T1.y);
    v[5] = make_float2(E1.x - T1.x, E1.y - T1.y);
    v[2] = make_float2(E2.x + T2.x, E2.y + T2.y);
    v[6] = make_float2(E2.x - T2.x, E2.y - T2.y);
    v[3] = make_float2(E3.x + T3.x, E3.y + T3.y);
    v[7] = make_float2(E3.x - T3.x, E3.y - T3.y);
}

// apply v[m] *= W^m for m=1..7, W=(wr,wi)  (low-register sequential chain)
__device__ __forceinline__ void twchain(float2 v[8], float wr, float wi) {
    float2 w = make_float2(wr, wi), cur = w;
    #pragma unroll
    for (int m = 1; m < 8; ++m) { v[m] = cmul(v[m], cur); cur = cmul(cur, w); }
}

// stage s=8: read Cb[t+64m] (free), dft8, twiddle, write Cb[64a+r+8m] (4-way)
__device__ __forceinline__ void r8_stage2(float2* Cb, const float* gtwr,
                                          const float* gtwi, int t, float sgn) {
    float2 u[8];
    #pragma unroll
    for (int m = 0; m < 8; ++m) u[m] = Cb[PC(t + 64 * m)];
    dft8(u, sgn);
    int a = t >> 3;
    twchain(u, gtwr[16 * a], sgn * gtwi[16 * a]);      // W_64^a = W_1024^{16a}
    int o1 = 64 * a + (t & 7);
    #pragma unroll
    for (int m = 0; m < 8; ++m) Cb[PC(o1 + 8 * m)] = u[m];
}

// window pair (win[2mp], win[2mp+1]) from the fp32 HALF table wtab[0..512]
// via symmetry win[j] = win[1024-j]. Branch is uniform per unrolled m
// (mp = t + 64m, t<64). mp<256: aligned float2. mp>=256: two b32, stride-2
// across lanes (free 2-way).
__device__ __forceinline__ float2 wread(const float* wtab, int mp) {
    if (mp < 256) {
        return *(const float2*)(wtab + 2 * mp);
    } else {
        return make_float2(wtab[1024 - 2 * mp], wtab[1023 - 2 * mp]);
    }
}

// -------- hot GL iteration: LDS = C (4*575*8 = 18400 B) + fp32 half-window
// (513*4 = 2052 B) = 20452 B <= 20480 -> 8 blocks/CU AND all window reads
// from LDS at fp32 (r14's fp16 window failed: win enters twice/iter vs fp32
// envinv -> systematic gain error x60). Window*SC folded into inverse
// writeback; OLA is pure LDS add.
__global__ __launch_bounds__(256, 4) void k_gl8(
        const float* __restrict__ Pin, const float* __restrict__ mag,
        const float* __restrict__ envinv,
        const float* __restrict__ gtwr, const float* __restrict__ gtwi,
        const float* __restrict__ win, float* __restrict__ Pout) {
    __shared__ __align__(16) unsigned char smem_raw[CHUNKF * C_SZ * sizeof(float2)];
    __shared__ float wtab[513];                    // fp32 half window
    float2 (*C)[C_SZ] = reinterpret_cast<float2(*)[C_SZ]>(smem_raw);
    float*  sigwin  = reinterpret_cast<float*>(smem_raw);   // first 7168 B of C
    float2* sigwin2 = reinterpret_cast<float2*>(smem_raw);
    int blk = blockIdx.x; int b = blk >> 8; int c = blk & (NCHUNK - 1);
    int tid = threadIdx.x; int g = tid >> 6; int t = tid & 63;
    // ---- stage normalized signal window (identical to verified round 6)
    const float* Pb = Pin + (size_t)b * NCHUNK * CSPAN;
    for (int q = tid; q < CSPAN; q += 256) {
        float v = Pb[c * CSPAN + q];
        if (q < 768 && c > 0)              v += Pb[(c - 1) * CSPAN + q + 1024];
        if (q >= 1024 && c < NCHUNK - 1)   v += Pb[(c + 1) * CSPAN + q - 1024];
        sigwin[q] = v * envinv[1024 * c + q];
    }
    // ---- build fp32 half-window table (once per block, coalesced)
    for (int e = tid; e < 513; e += 256) wtab[e] = win[e];
    __syncthreads();
    float2* Cb = C[g];
    int ft = CHUNKF * c + g;
    const float* mrow = mag + (size_t)(b * TFRAMES + ft) * NFREQ;
    // ---- z-pack into registers: z[m] = s[2mp]w[2mp] + i s[2mp+1]w[2mp+1]
    float2 v[8];
    if (c > 0 && c < NCHUNK - 1) {
        // no reflection possible: q index = 256g + 2mp -> contiguous float2
        #pragma unroll
        for (int m = 0; m < 8; ++m) {
            int mp = t + 64 * m;
            float2 sv = sigwin2[128 * g + mp];
            float2 w2 = wread(wtab, mp);
            v[m] = make_float2(sv.x * w2.x, sv.y * w2.y);
        }
    } else {
        #pragma unroll
        for (int m = 0; m < 8; ++m) {
            int mp = t + 64 * m;
            int js = 2 * mp;
            float sv[2];
            #pragma unroll
            for (int h = 0; h < 2; ++h) {
                int pp = 1024 * c + 256 * g + js + h;
                int u = pp - PADW;
                if (u < 0) u = -u;
                else if (u >= LOUT) u = 2 * LOUT - 2 - u;
                sv[h] = sigwin[u + PADW - 1024 * c];
            }
            float2 w2 = wread(wtab, mp);
            v[m] = make_float2(sv[0] * w2.x, sv[1] * w2.y);
        }
    }
    __syncthreads();   // sigwin fully consumed; C may now overwrite its space
    // ---- forward FFT
    dft8(v, +1.f);
    twchain(v, gtwr[2 * t], gtwi[2 * t]);               // W_512^t
    #pragma unroll
    for (int m = 0; m < 8; ++m) Cb[PC(8 * t + m)] = v[m];
    r8_stage2(Cb, gtwr, gtwi, t, +1.f);
    // ---- forward stage s=64: Zp in registers, one LDS write-back (free)
    float2 Zp[8];
    #pragma unroll
    for (int m = 0; m < 8; ++m) Zp[m] = Cb[PC(t + 64 * m)];
    dft8(Zp, +1.f);
    #pragma unroll
    for (int m = 0; m < 8; ++m) Cb[PC(t + 64 * m)] = Zp[m];
    // ---- projection; mirror bins JIT from LDS; fast rcp/sqrt
    #pragma unroll
    for (int m = 0; m < 8; ++m) {
        int p = t + 64 * m, q = 512 - p;
        float2 Zq = Cb[PC(q & 511)];
        float Ar = 0.5f * (Zp[m].x + Zq.x), Ai = 0.5f * (Zp[m].y - Zq.y);
        float Br = 0.5f * (Zp[m].x - Zq.x), Bi = 0.5f * (Zp[m].y + Zq.y);
        float Wr = gtwr[p & 511], Wi = gtwi[p & 511];
        float P = Wr * Bi + Wi * Br, Q = Wr * Br - Wi * Bi;
        float Xpr = Ar + P, Xpi = Ai - Q;
        float Xqr = Ar - P, Xqi = -Ai - Q;
        float scp = mrow[p] * __builtin_amdgcn_rcpf(
            __builtin_amdgcn_sqrtf(Xpr * Xpr + Xpi * Xpi) + 1e-8f);
        float scq = mrow[q & 1023] * __builtin_amdgcn_rcpf(
            __builtin_amdgcn_sqrtf(Xqr * Xqr + Xqi * Xqi) + 1e-8f);
        float ppr = Xpr * scp, ppi = Xpi * scp;
        float pqr = Xqr * scq, pqi = Xqi * scq;
        float Cr = 0.5f * (ppr + pqr), Ci = 0.5f * (ppi - pqi);
        float Dr = 0.5f * (ppr - pqr), Di = 0.5f * (ppi + pqi);
        float U = Wr * Di - Wi * Dr, V = Wr * Dr + Wi * Di;
        v[m] = make_float2(Cr - U, Ci + V);
    }
    if (t == 0) {
        float2 Z0 = Zp[0];
        float X0 = Z0.x + Z0.y, X512 = Z0.x - Z0.y;
        float p0   = mrow[0]   * X0   * __builtin_amdgcn_rcpf(fabsf(X0)   + 1e-8f);
        float p512 = mrow[512] * X512 * __builtin_amdgcn_rcpf(fabsf(X512) + 1e-8f);
        v[0] = make_float2(0.5f * (p0 + p512), 0.5f * (p0 - p512));
        float2 Zc = Zp[4];
        float X256r = Zc.x, X256i = -Zc.y;
        float sc = mrow[256] * __builtin_amdgcn_rcpf(
            __builtin_amdgcn_sqrtf(X256r * X256r + X256i * X256i) + 1e-8f);
        v[4] = make_float2(X256r * sc, -(X256i * sc));
    }
    // ---- inverse FFT; stage-1 consumes projection registers directly
    dft8(v, -1.f);
    twchain(v, gtwr[2 * t], -gtwi[2 * t]);              // conj for inverse
    #pragma unroll
    for (int m = 0; m < 8; ++m) Cb[PC(8 * t + m)] = v[m];
    r8_stage2(Cb, gtwr, gtwi, t, -1.f);
    // inverse stage s=64: apply synthesis window * (1/512) in registers at
    // writeback — u[m] holds samples x[2(t+64m)], x[2(t+64m)+1]
    {
        const float SC = 1.0f / 512.0f;
        float2 u[8];
        #pragma unroll
        for (int m = 0; m < 8; ++m) u[m] = Cb[PC(t + 64 * m)];
        dft8(u, -1.f);
        #pragma unroll
        for (int m = 0; m < 8; ++m) {
            float2 w2 = wread(wtab, t + 64 * m);
            Cb[PC(t + 64 * m)] = make_float2(u[m].x * w2.x * SC,
                                             u[m].y * w2.y * SC);
        }
    }
    __syncthreads();
    // ---- intra-block OLA of 4 frames -> Pout[c]  (pure LDS add; window
    //      and scale already applied in the writeback above)
    float* Po = Pout + ((size_t)b * NCHUNK + c) * CSPAN;
    for (int j = tid; j < CSPAN; j += 256) {
        float acc = 0.f;
        #pragma unroll
        for (int gg = 0; gg < CHUNKF; ++gg) {
            int p = j - 256 * gg;
            if (p >= 0 && p < NFFT) {
                float2 zz = C[gg][PC(p >> 1)];
                acc += (p & 1) ? zz.y : zz.x;
            }
        }
        Po[j] = acc;
    }
}

// -------------------- final output (verified round 6)
__global__ void k_out(const float* __restrict__ P, const float* __restrict__ envinv,
                      float* __restrict__ out) {
    int i = blockIdx.x * 256 + threadIdx.x;
    int b = blockIdx.y;
    if (i >= LOUT) return;
    int ii = i + PADW;
    int c = ii >> 10; if (c > NCHUNK - 1) c = NCHUNK - 1;
    const float* Pb = P + (size_t)b * NCHUNK * CSPAN;
    int j = ii - 1024 * c;
    float v = Pb[c * CSPAN + j];
    if (c > 0) {
        int j2 = j + 1024;
        if (j2 < CSPAN) v += Pb[(c - 1) * CSPAN + j2];
    }
    out[(size_t)b * LOUT + i] = v * envinv[ii];
}

// ---------------------------------------------------------------------- host
extern "C" void kernel_launch(void* const* d_in, const int* in_sizes, int n_in,
                              void* d_out, int out_size, void* d_ws, size_t ws_size,
                              hipStream_t stream) {
    const float* mel = (const float*)d_in[0];   // (8, 80, 1024)
    const float* ang = (const float*)d_in[1];   // (8, 513, 1024)
    const float* fb  = (const float*)d_in[2];   // (513, 80)
    float* ws = (float*)d_ws;

    float* twr    = ws;                                   // 512   (W_1024)
    float* twi    = twr + NHALF;                          // 512
    float* t5r    = twi + NHALF;                          // 128   (W_512, init)
    float* t5i    = t5r + 128;                            // 128
    float* win    = t5i + 128;                            // 1024
    float* fbT    = win + NFFT;                           // 80*513
    float* envinv = fbT + NMELS * NFREQ;                  // LPAD
    float* mag    = envinv + LPAD;                        // 8*1024*513
    float* PA     = mag + (size_t)BATCH * TFRAMES * NFREQ;    // 8*256*1792
    float* PB     = PA + (size_t)BATCH * NCHUNK * CSPAN;      // 8*256*1792
    float* out    = (float*)d_out;

    k_init_tables<<<4, 256, 0, stream>>>(twr, twi, t5r, t5i, win);
    k_env<<<(LPAD + 255) / 256, 256, 0, stream>>>(win, envinv);
    k_fbt<<<(NFREQ * NMELS + 255) / 256, 256, 0, stream>>>(fb, fbT);
    {
        dim3 g(TFRAMES / 16, BATCH);
        k_mag<<<g, 256, 0, stream>>>(mel, fbT, mag);
    }
    k_init4<<<BATCH * NCHUNK, 512, 0, stream>>>(mag, ang, twr, twi, t5r, t5i, win, PA);

    float* fin = PA;
    float* fout = PB;
    for (int it = 0; it < NITER; ++it) {
        k_gl8<<<BATCH * NCHUNK, 256, 0, stream>>>(fin, mag, envinv, twr, twi,
                                                  win, fout);
        float* tmp = fin; fin = fout; fout = tmp;
    }
    dim3 og((LOUT + 255) / 256, BATCH);
    k_out<<<og, 256, 0, stream>>>(fin, envinv, out);
}

// Round 17
// 1663.446 us; speedup vs baseline: 1.2581x; 1.1590x over previous
//
#include <hip/hip_runtime.h>
#include <math.h>

#define NFFT   1024
#define NHALF  512
#define HOPSZ  256
#define NMELS  80
#define NFREQ  513
#define BATCH  8
#define TFRAMES 1024
#define PADW   512
#define LPAD   (NFFT + (TFRAMES - 1) * HOPSZ)   // 262912
#define LOUT   (LPAD - 2 * PADW)                // 261888
#define NITER  60
#define PI_D   3.14159265358979323846

#define CHUNKF 4                                // frames per chunk
#define CSPAN  1792                             // 1024 + 3*256
#define NCHUNK (TFRAMES / CHUNKF)               // 256

// padding for the (old, init-only) radix-4 FFT
#define PAD(p) ((p) + ((p) >> 5))
#define NPAD   (NHALF + (NHALF >> 5))           // 528

// padding for the hot-loop radix-8 C buffer (float2 units): +1 per 8
// max used index PC(511)=574 -> 575 entries suffice
#define PC(p)  ((p) + ((p) >> 3))
#define C_SZ   575

// ---------------------------------------------------------------- init tables
__global__ void k_init_tables(float* __restrict__ twr, float* __restrict__ twi,
                              float* __restrict__ t5r, float* __restrict__ t5i,
                              float* __restrict__ win) {
    int j = blockIdx.x * 256 + threadIdx.x;
    if (j < NHALF) {
        double th = -2.0 * PI_D * (double)j / (double)NFFT;
        twr[j] = (float)cos(th);
        twi[j] = (float)sin(th);
    }
    if (j < 128) {
        double th = -2.0 * PI_D * (double)j / 512.0;
        t5r[j] = (float)cos(th);
        t5i[j] = (float)sin(th);
    }
    if (j < NFFT) {
        win[j] = (float)(0.5 - 0.5 * cos(2.0 * PI_D * (double)j / (double)NFFT));
    }
}

__global__ void k_env(const float* __restrict__ win, float* __restrict__ envinv) {
    int i = blockIdx.x * 256 + threadIdx.x;
    if (i >= LPAD) return;
    int thi = i / HOPSZ; if (thi > TFRAMES - 1) thi = TFRAMES - 1;
    int d = i - (NFFT - 1);
    int tlo = (d > 0) ? (d + HOPSZ - 1) / HOPSZ : 0;
    float e = 0.f;
    for (int t = tlo; t <= thi; ++t) { float w = win[i - t * HOPSZ]; e += w * w; }
    envinv[i] = (e > 1e-11f) ? (1.0f / e) : 1.0f;
}

__global__ void k_fbt(const float* __restrict__ fb, float* __restrict__ fbT) {
    int i = blockIdx.x * 256 + threadIdx.x;
    if (i < NFREQ * NMELS) {
        int k = i / NMELS, m = i - k * NMELS;
        fbT[m * NFREQ + k] = fb[i];
    }
}

// mag[(b*1024+t)*513+k], tiled 16 t per block
__global__ __launch_bounds__(256) void k_mag(const float* __restrict__ mel,
                                             const float* __restrict__ fbT,
                                             float* __restrict__ mag) {
    __shared__ float sm[NMELS * 16];
    int b = blockIdx.y, t0 = blockIdx.x * 16, tid = threadIdx.x;
    for (int idx = tid; idx < NMELS * 16; idx += 256) {
        int m = idx >> 4, tt = idx & 15;
        sm[idx] = expf(mel[(size_t)(b * NMELS + m) * TFRAMES + (t0 + tt)]);
    }
    __syncthreads();
    for (int k = tid; k < NFREQ; k += 256) {
        float acc[16];
        #pragma unroll
        for (int tt = 0; tt < 16; ++tt) acc[tt] = 0.f;
        for (int m = 0; m < NMELS; ++m) {
            float w = fbT[m * NFREQ + k];
            #pragma unroll
            for (int tt = 0; tt < 16; ++tt) acc[tt] += w * sm[m * 16 + tt];
        }
        #pragma unroll
        for (int tt = 0; tt < 16; ++tt)
            mag[(size_t)((b << 10) + t0 + tt) * NFREQ + k] = fmaxf(acc[tt], 0.f);
    }
}

// ===================== old radix-4 path (init kernel only, verified round 6)
__device__ __forceinline__ void fft512_m(float* xr, float* xi, float* yr, float* yi,
                                         const float* t5r, const float* t5i,
                                         int l, float sgn) {
    float *ar = xr, *ai = xi, *br = yr, *bi = yi;
    #pragma unroll
    for (int st = 0; st < 4; ++st) {
        int s = 1 << (2 * st);
        __syncthreads();
        int j = l;
        int hi = j & ~(s - 1);
        int o1 = j + 3 * hi;
        float v0r = ar[PAD(j)],       v0i = ai[PAD(j)];
        float v1r = ar[PAD(j + 128)], v1i = ai[PAD(j + 128)];
        float v2r = ar[PAD(j + 256)], v2i = ai[PAD(j + 256)];
        float v3r = ar[PAD(j + 384)], v3i = ai[PAD(j + 384)];
        float a_r = v0r + v2r, a_i = v0i + v2i;
        float b_r = v0r - v2r, b_i = v0i - v2i;
        float c_r = v1r + v3r, c_i = v1i + v3i;
        float d_r = v1r - v3r, d_i = v1i - v3i;
        float X0r = a_r + c_r, X0i = a_i + c_i;
        float X2r = a_r - c_r, X2i = a_i - c_i;
        float X1r = b_r + sgn * d_i, X1i = b_i - sgn * d_r;
        float X3r = b_r - sgn * d_i, X3i = b_i + sgn * d_r;
        float w1r = t5r[hi], w1i = sgn * t5i[hi];
        float w2r = w1r * w1r - w1i * w1i, w2i = 2.f * w1r * w1i;
        float w3r = w2r * w1r - w2i * w1i, w3i = w2r * w1i + w2i * w1r;
        br[PAD(o1)]         = X0r;
        bi[PAD(o1)]         = X0i;
        br[PAD(o1 + s)]     = X1r * w1r - X1i * w1i;
        bi[PAD(o1 + s)]     = X1r * w1i + X1i * w1r;
        br[PAD(o1 + 2*s)]   = X2r * w2r - X2i * w2i;
        bi[PAD(o1 + 2*s)]   = X2r * w2i + X2i * w2r;
        br[PAD(o1 + 3*s)]   = X3r * w3r - X3i * w3i;
        bi[PAD(o1 + 3*s)]   = X3r * w3i + X3i * w3r;
        float* t0 = ar; ar = br; br = t0;
        float* t1 = ai; ai = bi; bi = t1;
    }
    __syncthreads();
    #pragma unroll
    for (int r = 0; r < 2; ++r) {
        int j = l + r * 128;
        float x0r = ar[PAD(j)],       x0i = ai[PAD(j)];
        float x1r = ar[PAD(j + 256)], x1i = ai[PAD(j + 256)];
        br[PAD(j)]       = x0r + x1r;
        bi[PAD(j)]       = x0i + x1i;
        br[PAD(j + 256)] = x0r - x1r;
        bi[PAD(j + 256)] = x0i - x1i;
    }
}

__device__ __forceinline__ void chunk_ola4(float (*Yr)[NPAD], float (*Yi)[NPAD],
                                           const float* swin, float* Po, int tid) {
    const float SC = 1.0f / 512.0f;
    for (int j = tid; j < CSPAN; j += 512) {
        float acc = 0.f;
        #pragma unroll
        for (int gg = 0; gg < CHUNKF; ++gg) {
            int p = j - 256 * gg;
            if (p >= 0 && p < NFFT) {
                float yv = (p & 1) ? Yi[gg][PAD(p >> 1)] : Yr[gg][PAD(p >> 1)];
                acc += yv * swin[p];
            }
        }
        Po[j] = acc * SC;
    }
}

// -------------------- init: P0 from mag * e^{i 2pi ang} (verified round 6)
__global__ __launch_bounds__(512) void k_init4(
        const float* __restrict__ mag, const float* __restrict__ ang,
        const float* __restrict__ gtwr, const float* __restrict__ gtwi,
        const float* __restrict__ gt5r, const float* __restrict__ gt5i,
        const float* __restrict__ win, float* __restrict__ Pout) {
    __shared__ float swin[NFFT];
    __shared__ float Xr[CHUNKF][NPAD], Xi[CHUNKF][NPAD];
    __shared__ float Yr[CHUNKF][NPAD], Yi[CHUNKF][NPAD];
    __shared__ float t5r[128], t5i[128];
    int blk = blockIdx.x; int b = blk >> 8; int c = blk & (NCHUNK - 1);
    int tid = threadIdx.x; int g = tid >> 7; int l = tid & 127;
    if (tid < 128) { t5r[tid] = gt5r[tid]; t5i[tid] = gt5i[tid]; }
    for (int q = tid; q < NFFT; q += 512) swin[q] = win[q];
    int ft = CHUNKF * c + g;
    const float* mrow = mag + (size_t)(b * TFRAMES + ft) * NFREQ;
    const float TWO_PI = 6.283185307179586477f;
    if (l == 0) {
        float a0, s0, c0;
        a0 = ang[((size_t)(b * NFREQ + 0)) * TFRAMES + ft] * TWO_PI;
        sincosf(a0, &s0, &c0);
        float p0 = mrow[0] * c0;
        a0 = ang[((size_t)(b * NFREQ + 512)) * TFRAMES + ft] * TWO_PI;
        sincosf(a0, &s0, &c0);
        float p512 = mrow[512] * c0;
        Xr[g][PAD(0)] = 0.5f * (p0 + p512);
        Xi[g][PAD(0)] = 0.5f * (p0 - p512);
        a0 = ang[((size_t)(b * NFREQ + 256)) * TFRAMES + ft] * TWO_PI;
        sincosf(a0, &s0, &c0);
        Xr[g][PAD(256)] = mrow[256] * c0;
        Xi[g][PAD(256)] = -(mrow[256] * s0);
    }
    #pragma unroll
    for (int q2 = 0; q2 < 2; ++q2) {
        int k = l + q2 * 128;
        if (k == 0) continue;
        int j = 512 - k;
        float ak = ang[((size_t)(b * NFREQ + k)) * TFRAMES + ft] * TWO_PI;
        float aj = ang[((size_t)(b * NFREQ + j)) * TFRAMES + ft] * TWO_PI;
        float sk, ck, sj, cj;
        sincosf(ak, &sk, &ck); sincosf(aj, &sj, &cj);
        float pkr = mrow[k] * ck, pki = mrow[k] * sk;
        float pjr = mrow[j] * cj, pji = mrow[j] * sj;
        float Wr = gtwr[k], Wi = gtwi[k];
        float Cr = 0.5f * (pkr + pjr), Ci = 0.5f * (pki - pji);
        float Dr = 0.5f * (pkr - pjr), Di = 0.5f * (pki + pji);
        float U = Wr * Di - Wi * Dr, V = Wr * Dr + Wi * Di;
        Xr[g][PAD(k)] = Cr - U;  Xi[g][PAD(k)] = Ci + V;
        Xr[g][PAD(j)] = Cr + U;  Xi[g][PAD(j)] = -Ci + V;
    }
    fft512_m(Xr[g], Xi[g], Yr[g], Yi[g], t5r, t5i, l, -1.f);
    __syncthreads();
    chunk_ola4(Yr, Yi, swin, Pout + ((size_t)b * NCHUNK + c) * CSPAN, tid);
}

// ===================== wave-local radix-8 machinery (hot loop) ==============
__device__ __forceinline__ float2 cmul(float2 a, float2 b) {
    return make_float2(a.x * b.x - a.y * b.y, a.x * b.y + a.y * b.x);
}

// in-register 8-pt DFT; sgn=+1 forward, -1 inverse (verified round 7)
__device__ __forceinline__ void dft8(float2 v[8], float sgn) {
    const float s2 = 0.70710678118654752f;
    float ar = v[0].x + v[4].x, ai = v[0].y + v[4].y;
    float br = v[0].x - v[4].x, bi = v[0].y - v[4].y;
    float cr = v[2].x + v[6].x, ci = v[2].y + v[6].y;
    float dr = v[2].x - v[6].x, di = v[2].y - v[6].y;
    float2 E0 = make_float2(ar + cr, ai + ci);
    float2 E2 = make_float2(ar - cr, ai - ci);
    float2 E1 = make_float2(br + sgn * di, bi - sgn * dr);
    float2 E3 = make_float2(br - sgn * di, bi + sgn * dr);
    float ar2 = v[1].x + v[5].x, ai2 = v[1].y + v[5].y;
    float br2 = v[1].x - v[5].x, bi2 = v[1].y - v[5].y;
    float cr2 = v[3].x + v[7].x, ci2 = v[3].y + v[7].y;
    float dr2 = v[3].x - v[7].x, di2 = v[3].y - v[7].y;
    float2 O0 = make_float2(ar2 + cr2, ai2 + ci2);
    float2 O2 = make_float2(ar2 - cr2, ai2 - ci2);
    float2 O1 = make_float2(br2 + sgn * di2, bi2 - sgn * dr2);
    float2 O3 = make_float2(br2 - sgn * di2, bi2 + sgn * dr2);
    float2 T1 = make_float2((O1.x + sgn * O1.y) * s2, (O1.y - sgn * O1.x) * s2);
    float2 T2 = make_float2(sgn * O2.y, -sgn * O2.x);
    float2 T3 = make_float2((-O3.x + sgn * O3.y) * s2, (-O3.y - sgn * O3.x) * s2);
    v[0] = make_float2(E0.x + O0.x, E0.y + O0.y);
    v[4] = make_float2(E0.x - O0.x, E0.y - O0.y);
    v[1] = make_float2(E1.x + T1.x, E1.y + T1.y);
    v[5] = make_float2(E1.x - T1.x, E1.y - T1.y);
    v[2] = make_float2(E2.x + T2.x, E2.y + T2.y);
    v[6] = make_float2(E2.x - T2.x, E2.y - T2.y);
    v[3] = make_float2(E3.x + T3.x, E3.y + T3.y);
    v[7] = make_float2(E3.x - T3.x, E3.y - T3.y);
}

// apply v[m] *= W^m for m=1..7, W=(wr,wi)  (low-register sequential chain)
__device__ __forceinline__ void twchain(float2 v[8], float wr, float wi) {
    float2 w = make_float2(wr, wi), cur = w;
    #pragma unroll
    for (int m = 1; m < 8; ++m) { v[m] = cmul(v[m], cur); cur = cmul(cur, w); }
}

// stage s=8: read Cb[t+64m] (free), dft8, twiddle, write Cb[64a+r+8m] (4-way)
__device__ __forceinline__ void r8_stage2(float2* Cb, const float* gtwr,
                                          const float* gtwi, int t, float sgn) {
    float2 u[8];
    #pragma unroll
    for (int m = 0; m < 8; ++m) u[m] = Cb[PC(t + 64 * m)];
    dft8(u, sgn);
    int a = t >> 3;
    twchain(u, gtwr[16 * a], sgn * gtwi[16 * a]);      // W_64^a = W_1024^{16a}
    int o1 = 64 * a + (t & 7);
    #pragma unroll
    for (int m = 0; m < 8; ++m) Cb[PC(o1 + 8 * m)] = u[m];
}

// window pair (win[2mp], win[2mp+1]) from the fp32 HALF table wtab[0..512]
// via symmetry win[j] = win[1024-j].
__device__ __forceinline__ float2 wread(const float* wtab, int mp) {
    if (mp < 256) {
        return *(const float2*)(wtab + 2 * mp);
    } else {
        return make_float2(wtab[1024 - 2 * mp], wtab[1023 - 2 * mp]);
    }
}

// -------- hot GL iteration (round-15 structure, staging/OLA vectorized):
//  LDS = C (18400 B) + fp32 half-window (2052 B) = 20452 <= 20480 -> 8 blk/CU;
//  staging float4 (halo conditions fall exactly on float4 boundaries;
//  R-halo base pointer already embeds the -1024 offset -> index is q4, NOT
//  q4-256: round-16's double-subtraction bug); OLA processes even/odd pairs.
__global__ __launch_bounds__(256, 4) void k_gl8(
        const float* __restrict__ Pin, const float* __restrict__ mag,
        const float* __restrict__ envinv,
        const float* __restrict__ gtwr, const float* __restrict__ gtwi,
        const float* __restrict__ win, float* __restrict__ Pout) {
    __shared__ __align__(16) unsigned char smem_raw[CHUNKF * C_SZ * sizeof(float2)];
    __shared__ float wtab[513];                    // fp32 half window
    float2 (*C)[C_SZ] = reinterpret_cast<float2(*)[C_SZ]>(smem_raw);
    float*  sigwin  = reinterpret_cast<float*>(smem_raw);   // first 7168 B of C
    float2* sigwin2 = reinterpret_cast<float2*>(smem_raw);
    float4* sig4    = reinterpret_cast<float4*>(smem_raw);
    int blk = blockIdx.x; int b = blk >> 8; int c = blk & (NCHUNK - 1);
    int tid = threadIdx.x; int g = tid >> 6; int t = tid & 63;
    // ---- stage normalized signal window, float4 (semantics = round 6 scalar)
    const float* Pb = Pin + (size_t)b * NCHUNK * CSPAN;
    {
        const float4* PbC = (const float4*)(Pb + c * CSPAN);
        const float4* PbL = (const float4*)(Pb + (c - 1) * CSPAN + 1024);
        const float4* PbR = (const float4*)(Pb + (c + 1) * CSPAN - 1024);
        const float4* env4 = (const float4*)(envinv + 1024 * c);
        for (int q4 = tid; q4 < 448; q4 += 256) {
            float4 v4 = PbC[q4];
            if (q4 < 192 && c > 0) {               // q < 768
                float4 h = PbL[q4];                // (c-1)*CSPAN + 1024 + 4*q4
                v4.x += h.x; v4.y += h.y; v4.z += h.z; v4.w += h.w;
            }
            if (q4 >= 256 && c < NCHUNK - 1) {     // q >= 1024
                float4 h = PbR[q4];                // (c+1)*CSPAN - 1024 + 4*q4
                v4.x += h.x; v4.y += h.y; v4.z += h.z; v4.w += h.w;
            }
            float4 e = env4[q4];
            sig4[q4] = make_float4(v4.x * e.x, v4.y * e.y, v4.z * e.z, v4.w * e.w);
        }
    }
    // ---- build fp32 half-window table (once per block, coalesced)
    for (int e = tid; e < 513; e += 256) wtab[e] = win[e];
    __syncthreads();
    float2* Cb = C[g];
    int ft = CHUNKF * c + g;
    const float* mrow = mag + (size_t)(b * TFRAMES + ft) * NFREQ;
    // ---- z-pack into registers: z[m] = s[2mp]w[2mp] + i s[2mp+1]w[2mp+1]
    float2 v[8];
    if (c > 0 && c < NCHUNK - 1) {
        #pragma unroll
        for (int m = 0; m < 8; ++m) {
            int mp = t + 64 * m;
            float2 sv = sigwin2[128 * g + mp];
            float2 w2 = wread(wtab, mp);
            v[m] = make_float2(sv.x * w2.x, sv.y * w2.y);
        }
    } else {
        #pragma unroll
        for (int m = 0; m < 8; ++m) {
            int mp = t + 64 * m;
            int js = 2 * mp;
            float sv[2];
            #pragma unroll
            for (int h = 0; h < 2; ++h) {
                int pp = 1024 * c + 256 * g + js + h;
                int u = pp - PADW;
                if (u < 0) u = -u;
                else if (u >= LOUT) u = 2 * LOUT - 2 - u;
                sv[h] = sigwin[u + PADW - 1024 * c];
            }
            float2 w2 = wread(wtab, mp);
            v[m] = make_float2(sv[0] * w2.x, sv[1] * w2.y);
        }
    }
    __syncthreads();   // sigwin fully consumed; C may now overwrite its space
    // ---- forward FFT
    dft8(v, +1.f);
    twchain(v, gtwr[2 * t], gtwi[2 * t]);               // W_512^t
    #pragma unroll
    for (int m = 0; m < 8; ++m) Cb[PC(8 * t + m)] = v[m];
    r8_stage2(Cb, gtwr, gtwi, t, +1.f);
    // ---- forward stage s=64: Zp in registers, one LDS write-back (free)
    float2 Zp[8];
    #pragma unroll
    for (int m = 0; m < 8; ++m) Zp[m] = Cb[PC(t + 64 * m)];
    dft8(Zp, +1.f);
    #pragma unroll
    for (int m = 0; m < 8; ++m) Cb[PC(t + 64 * m)] = Zp[m];
    // ---- projection; mirror bins JIT from LDS; fast rcp/sqrt
    #pragma unroll
    for (int m = 0; m < 8; ++m) {
        int p = t + 64 * m, q = 512 - p;
        float2 Zq = Cb[PC(q & 511)];
        float Ar = 0.5f * (Zp[m].x + Zq.x), Ai = 0.5f * (Zp[m].y - Zq.y);
        float Br = 0.5f * (Zp[m].x - Zq.x), Bi = 0.5f * (Zp[m].y + Zq.y);
        float Wr = gtwr[p & 511], Wi = gtwi[p & 511];
        float P = Wr * Bi + Wi * Br, Q = Wr * Br - Wi * Bi;
        float Xpr = Ar + P, Xpi = Ai - Q;
        float Xqr = Ar - P, Xqi = -Ai - Q;
        float scp = mrow[p] * __builtin_amdgcn_rcpf(
            __builtin_amdgcn_sqrtf(Xpr * Xpr + Xpi * Xpi) + 1e-8f);
        float scq = mrow[q & 1023] * __builtin_amdgcn_rcpf(
            __builtin_amdgcn_sqrtf(Xqr * Xqr + Xqi * Xqi) + 1e-8f);
        float ppr = Xpr * scp, ppi = Xpi * scp;
        float pqr = Xqr * scq, pqi = Xqi * scq;
        float Cr = 0.5f * (ppr + pqr), Ci = 0.5f * (ppi - pqi);
        float Dr = 0.5f * (ppr - pqr), Di = 0.5f * (ppi + pqi);
        float U = Wr * Di - Wi * Dr, V = Wr * Dr + Wi * Di;
        v[m] = make_float2(Cr - U, Ci + V);
    }
    if (t == 0) {
        float2 Z0 = Zp[0];
        float X0 = Z0.x + Z0.y, X512 = Z0.x - Z0.y;
        float p0   = mrow[0]   * X0   * __builtin_amdgcn_rcpf(fabsf(X0)   + 1e-8f);
        float p512 = mrow[512] * X512 * __builtin_amdgcn_rcpf(fabsf(X512) + 1e-8f);
        v[0] = make_float2(0.5f * (p0 + p512), 0.5f * (p0 - p512));
        float2 Zc = Zp[4];
        float X256r = Zc.x, X256i = -Zc.y;
        float sc = mrow[256] * __builtin_amdgcn_rcpf(
            __builtin_amdgcn_sqrtf(X256r * X256r + X256i * X256i) + 1e-8f);
        v[4] = make_float2(X256r * sc, -(X256i * sc));
    }
    // ---- inverse FFT; stage-1 consumes projection registers directly
    dft8(v, -1.f);
    twchain(v, gtwr[2 * t], -gtwi[2 * t]);              // conj for inverse
    #pragma unroll
    for (int m = 0; m < 8; ++m) Cb[PC(8 * t + m)] = v[m];
    r8_stage2(Cb, gtwr, gtwi, t, -1.f);
    // inverse stage s=64: apply synthesis window * (1/512) at writeback
    {
        const float SC = 1.0f / 512.0f;
        float2 u[8];
        #pragma unroll
        for (int m = 0; m < 8; ++m) u[m] = Cb[PC(t + 64 * m)];
        dft8(u, -1.f);
        #pragma unroll
        for (int m = 0; m < 8; ++m) {
            float2 w2 = wread(wtab, t + 64 * m);
            Cb[PC(t + 64 * m)] = make_float2(u[m].x * w2.x * SC,
                                             u[m].y * w2.y * SC);
        }
    }
    __syncthreads();
    // ---- intra-block OLA, even/odd pairs: tap float2 serves both outputs
    float2* Po2 = (float2*)(Pout + ((size_t)b * NCHUNK + c) * CSPAN);
    for (int j2 = tid; j2 < 896; j2 += 256) {
        float2 acc = make_float2(0.f, 0.f);
        #pragma unroll
        for (int gg = 0; gg < CHUNKF; ++gg) {
            int p2 = j2 - 128 * gg;                // = (j - 256*gg)/2
            if (p2 >= 0 && p2 < 512) {
                float2 zz = C[gg][PC(p2)];
                acc.x += zz.x; acc.y += zz.y;
            }
        }
        Po2[j2] = acc;
    }
}

// -------------------- final output (verified round 6)
__global__ void k_out(const float* __restrict__ P, const float* __restrict__ envinv,
                      float* __restrict__ out) {
    int i = blockIdx.x * 256 + threadIdx.x;
    int b = blockIdx.y;
    if (i >= LOUT) return;
    int ii = i + PADW;
    int c = ii >> 10; if (c > NCHUNK - 1) c = NCHUNK - 1;
    const float* Pb = P + (size_t)b * NCHUNK * CSPAN;
    int j = ii - 1024 * c;
    float v = Pb[c * CSPAN + j];
    if (c > 0) {
        int j2 = j + 1024;
        if (j2 < CSPAN) v += Pb[(c - 1) * CSPAN + j2];
    }
    out[(size_t)b * LOUT + i] = v * envinv[ii];
}

// ---------------------------------------------------------------------- host
extern "C" void kernel_launch(void* const* d_in, const int* in_sizes, int n_in,
                              void* d_out, int out_size, void* d_ws, size_t ws_size,
                              hipStream_t stream) {
    const float* mel = (const float*)d_in[0];   // (8, 80, 1024)
    const float* ang = (const float*)d_in[1];   // (8, 513, 1024)
    const float* fb  = (const float*)d_in[2];   // (513, 80)
    float* ws = (float*)d_ws;

    float* twr    = ws;                                   // 512   (W_1024)
    float* twi    = twr + NHALF;                          // 512
    float* t5r    = twi + NHALF;                          // 128   (W_512, init)
    float* t5i    = t5r + 128;                            // 128
    float* win    = t5i + 128;                            // 1024
    float* fbT    = win + NFFT;                           // 80*513
    float* envinv = fbT + NMELS * NFREQ;                  // LPAD
    float* mag    = envinv + LPAD;                        // 8*1024*513
    float* PA     = mag + (size_t)BATCH * TFRAMES * NFREQ;    // 8*256*1792
    float* PB     = PA + (size_t)BATCH * NCHUNK * CSPAN;      // 8*256*1792
    float* out    = (float*)d_out;

    k_init_tables<<<4, 256, 0, stream>>>(twr, twi, t5r, t5i, win);
    k_env<<<(LPAD + 255) / 256, 256, 0, stream>>>(win, envinv);
    k_fbt<<<(NFREQ * NMELS + 255) / 256, 256, 0, stream>>>(fb, fbT);
    {
        dim3 g(TFRAMES / 16, BATCH);
        k_mag<<<g, 256, 0, stream>>>(mel, fbT, mag);
    }
    k_init4<<<BATCH * NCHUNK, 512, 0, stream>>>(mag, ang, twr, twi, t5r, t5i, win, PA);

    float* fin = PA;
    float* fout = PB;
    for (int it = 0; it < NITER; ++it) {
        k_gl8<<<BATCH * NCHUNK, 256, 0, stream>>>(fin, mag, envinv, twr, twi,
                                                  win, fout);
        float* tmp = fin; fin = fout; fout = tmp;
    }
    dim3 og((LOUT + 255) / 256, BATCH);
    k_out<<<og, 256, 0, stream>>>(fin, envinv, out);
}